// Round 5
// baseline (531.249 us; speedup 1.0000x reference)
//
#include <hip/hip_runtime.h>
#include <math.h>

#define DIN  512
#define DHID 512
#define DOUT 256

typedef __attribute__((ext_vector_type(8))) short short8;
typedef __attribute__((ext_vector_type(4))) float f32x4;
typedef __attribute__((ext_vector_type(2))) float floatx2;

__device__ __forceinline__ unsigned short f2bf(float f) {
    unsigned int u = __float_as_uint(f);
    u += 0x7fffu + ((u >> 16) & 1u);
    return (unsigned short)(u >> 16);
}
__device__ __forceinline__ float bflo(unsigned int w) { return __uint_as_float(w << 16); }
__device__ __forceinline__ float bfhi(unsigned int w) { return __uint_as_float(w & 0xffff0000u); }

// ---------------------------------------------------------------------------
// fp32 -> bf16, 8 elems per index i
__device__ __forceinline__ void cvt8(const float* __restrict__ in,
                                     unsigned short* __restrict__ out, int i) {
    const float4* iv = (const float4*)in;
    float4 a = iv[2 * i], b = iv[2 * i + 1];
    uint4 o;
    o.x = (unsigned)f2bf(a.x) | ((unsigned)f2bf(a.y) << 16);
    o.y = (unsigned)f2bf(a.z) | ((unsigned)f2bf(a.w) << 16);
    o.z = (unsigned)f2bf(b.x) | ((unsigned)f2bf(b.y) << 16);
    o.w = (unsigned)f2bf(b.z) | ((unsigned)f2bf(b.w) << 16);
    ((uint4*)out)[i] = o;
}

__global__ void k_f2bf(const float* __restrict__ in, unsigned short* __restrict__ out, int n8) {
    int i = blockIdx.x * blockDim.x + threadIdx.x;
    if (i < n8) cvt8(in, out, i);
}

__global__ void k_wcvt(const float* __restrict__ W1l, const float* __restrict__ W1r,
                       const float* __restrict__ W2l, const float* __restrict__ W2r,
                       unsigned short* __restrict__ w1, unsigned short* __restrict__ w2) {
    int i = blockIdx.x * blockDim.x + threadIdx.x;
    if (i < 32768)        cvt8(W1l, w1, i);
    else if (i < 65536)   cvt8(W1r, w1 + 262144, i - 32768);
    else if (i < 81920)   cvt8(W2l, w2, i - 65536);
    else if (i < 98304)   cvt8(W2r, w2 + 131072, i - 81920);
}

// ---------------------------------------------------------------------------
// CSR build, both layers batched (blockIdx.y = layer)
__global__ void k_count2(const int* __restrict__ d1, const int* __restrict__ d2,
                         int* __restrict__ deg1, int* __restrict__ deg2, int E1, int E2) {
    int e = blockIdx.x * blockDim.x + threadIdx.x;
    if (blockIdx.y == 0) { if (e < E1) atomicAdd(&deg1[d1[e]], 1); }
    else                 { if (e < E2) atomicAdd(&deg2[d2[e]], 1); }
}

#define SCAN_B 256
__global__ void k_scan_partial2(const int* __restrict__ deg1, const int* __restrict__ deg2,
                                int* __restrict__ part1, int* __restrict__ part2, int n) {
    __shared__ int s[SCAN_B];
    const int* deg = blockIdx.y ? deg2 : deg1;
    int* part      = blockIdx.y ? part2 : part1;
    int i = blockIdx.x * SCAN_B + threadIdx.x;
    s[threadIdx.x] = (i < n) ? deg[i] : 0;
    __syncthreads();
    for (int off = SCAN_B / 2; off > 0; off >>= 1) {
        if (threadIdx.x < off) s[threadIdx.x] += s[threadIdx.x + off];
        __syncthreads();
    }
    if (threadIdx.x == 0) part[blockIdx.x] = s[0];
}

__global__ void k_scan_part2b(int* __restrict__ part1, int* __restrict__ part2, int nb,
                              int* __restrict__ rowptr1, int* __restrict__ rowptr2, int n) {
    __shared__ int s[SCAN_B];
    int* part   = blockIdx.x ? part2 : part1;
    int* rowptr = blockIdx.x ? rowptr2 : rowptr1;
    int v = (threadIdx.x < nb) ? part[threadIdx.x] : 0;
    s[threadIdx.x] = v;
    __syncthreads();
    for (int off = 1; off < SCAN_B; off <<= 1) {
        int t = (threadIdx.x >= off) ? s[threadIdx.x - off] : 0;
        __syncthreads();
        s[threadIdx.x] += t;
        __syncthreads();
    }
    if (threadIdx.x < nb) part[threadIdx.x] = s[threadIdx.x] - v;  // exclusive
    if (threadIdx.x == SCAN_B - 1) rowptr[n] = s[SCAN_B - 1];
}

__global__ void k_scan_final2(const int* __restrict__ deg1, const int* __restrict__ deg2,
                              const int* __restrict__ part1, const int* __restrict__ part2,
                              int* __restrict__ rowptr1, int* __restrict__ rowptr2,
                              int* __restrict__ cursor1, int* __restrict__ cursor2, int n) {
    __shared__ int s[SCAN_B];
    const int* deg  = blockIdx.y ? deg2 : deg1;
    const int* part = blockIdx.y ? part2 : part1;
    int* rowptr     = blockIdx.y ? rowptr2 : rowptr1;
    int* cursor     = blockIdx.y ? cursor2 : cursor1;
    int i = blockIdx.x * SCAN_B + threadIdx.x;
    int v = (i < n) ? deg[i] : 0;
    s[threadIdx.x] = v;
    __syncthreads();
    for (int off = 1; off < SCAN_B; off <<= 1) {
        int t = (threadIdx.x >= off) ? s[threadIdx.x - off] : 0;
        __syncthreads();
        s[threadIdx.x] += t;
        __syncthreads();
    }
    if (i < n) {
        int ex = part[blockIdx.x] + s[threadIdx.x] - v;
        rowptr[i] = ex;
        cursor[i] = ex;
    }
}

__global__ void k_fill2(const int* __restrict__ s1, const int* __restrict__ d1,
                        const int* __restrict__ s2, const int* __restrict__ d2,
                        int* __restrict__ cur1, int* __restrict__ cur2,
                        int* __restrict__ col1, int* __restrict__ col2, int E1, int E2) {
    int e = blockIdx.x * blockDim.x + threadIdx.x;
    if (blockIdx.y == 0) {
        if (e < E1) { int p = atomicAdd(&cur1[d1[e]], 1); col1[p] = s1[e]; }
    } else {
        if (e < E2) { int p = atomicAdd(&cur2[d2[e]], 1); col2[p] = s2[e]; }
    }
}

// ---------------------------------------------------------------------------
// Persistent 256-block, 2-phase-per-K-tile, 256x256 (BK=64) bf16 MFMA GEMM.
// 8 waves (2M x 4N), each owns 128x64 C = acc[8][4]. Double-buffered 128 KiB
// LDS, 1 block/CU. Per K-tile:
//   P0: vmcnt(2)+bar | stage [A0',B0'] | read A0,B0,B1 | MFMA rows0-3 x cols0-3
//   P1: vmcnt(4)+bar | stage [B1',A1'] | read A1       | MFMA rows4-7 x cols0-3
// Ledger (stage order per tile: A0,B0 @P0 then B1,A1 @P1, 2 loads each):
//   at P0 entry outstanding = 8 (prev tile's 4 pairs); need A0,B0,B1 ->
//   allow A1 pair -> vmcnt(2). At P1 entry outstanding = A1(2)+alpha'(4)=6;
//   need A1 -> vmcnt(4). Every operand has >=1 full phase (~1200cy) of
//   latency cover. Each counted vmcnt is followed by s_barrier (publish).
// Cross-tile: during the last K-tile the NEXT tile's kt0 is staged (bases
// recomputed); per-tile epilogue stores + vmcnt(0) drain overlap those loads.
// Final tile of a block: skip staging, P1 uses vmcnt(0).
// Dual-B register sets (b0,b1 retained across both phases) remove the A-h0
// re-read: 24 b128/wave/tile -> per-CU LDS-read (~2300cy) < MFMA (~2480cy).
// LDS swizzle identical to the verified round-3 kernel (0 bank conflicts).
// SPLIT=1: cols [0,NC/2) -> fp8 e4m3 C8, cols [NC/2,NC) -> bf16 C16.
#define BM 256
#define BN 256
#define BK 64
#define LDT (BM * BK)   // elems per matrix per buffer
#define PGRID 256

template <int NCT, int SPLIT>
__global__ __launch_bounds__(512, 2)
void k_gemm_p2(const unsigned short* __restrict__ A, const unsigned short* __restrict__ W,
               unsigned char* __restrict__ C8, unsigned short* __restrict__ C16,
               int M, int K, int NC, int ntiles) {
    __shared__ __align__(16) unsigned short As[2 * LDT];
    __shared__ __align__(16) unsigned short Bs[2 * LDT];

    const int bid = blockIdx.x;
    const int sid0 = (bid & 7) * (PGRID >> 3) + (bid >> 3);   // XCD-chunked
    if (sid0 >= ntiles) return;

    const int t = threadIdx.x;
    const int lane = t & 63;
    const int w = t >> 6;
    const int wm = w >> 2;            // 0..1
    const int wn = w & 3;             // 0..3
    const int lm = lane & 15;
    const int lq = lane >> 4;         // 0..3
    const int l7 = lm & 7;
    const int cx0 = (lq ^ l7) * 8;         // swizzled read offset, kstep 0
    const int cx1 = ((4 + lq) ^ l7) * 8;   // kstep 1

    // staging geometry: thread t stages 16B chunk (row rl(+...), slot cs).
    const int rl = t >> 3;                        // 0..63
    const int cs = t & 7;
    const int rB = ((rl >> 5) << 6) + (rl & 31);  // B half rows: 0-31 / 64-95
    const int kx = (cs ^ (rl & 7)) * 8;           // inverse-swizzled source chunk

    // LDS dest offsets (linear; swizzle lives in the global source + read)
    const int dA = rl * BK + cs * 8;
    const int dA00 = dA,            dA01 = dA + 128 * BK;     // A-h0 rows {0-63,128-191}
    const int dA10 = dA + 64 * BK,  dA11 = dA + 192 * BK;     // A-h1 rows {64-127,192-255}
    const int dB = rB * BK + cs * 8;
    const int dB00 = dB,            dB01 = dB + 128 * BK;     // B-h0
    const int dB10 = dB + 32 * BK,  dB11 = dB + 160 * BK;     // B-h1

    // staging source pointers: always point at the tile being STAGED
    const unsigned short *sA00, *sA01, *sA10, *sA11, *sB00, *sB01, *sB10, *sB11;
    #define COMPUTE_BASES(stix) do { \
        int _r0 = ((stix) / NCT) * BM; \
        int _c0 = ((stix) % NCT) * BN; \
        int _a0 = _r0 + rl;        if (_a0 >= M) _a0 = M - 1; \
        int _a1 = _r0 + rl + 128;  if (_a1 >= M) _a1 = M - 1; \
        int _a2 = _r0 + rl + 64;   if (_a2 >= M) _a2 = M - 1; \
        int _a3 = _r0 + rl + 192;  if (_a3 >= M) _a3 = M - 1; \
        sA00 = A + (size_t)_a0 * K + kx; \
        sA01 = A + (size_t)_a1 * K + kx; \
        sA10 = A + (size_t)_a2 * K + kx; \
        sA11 = A + (size_t)_a3 * K + kx; \
        sB00 = W + (size_t)(_c0 + rB) * K + kx; \
        sB01 = W + (size_t)(_c0 + rB + 128) * K + kx; \
        sB10 = W + (size_t)(_c0 + rB + 32) * K + kx; \
        sB11 = W + (size_t)(_c0 + rB + 160) * K + kx; \
    } while (0)

    #define GL(SRC, ARR, D) __builtin_amdgcn_global_load_lds( \
        (const __attribute__((address_space(1))) unsigned int*)(SRC), \
        (__attribute__((address_space(3))) unsigned int*)&ARR[D], 16, 0, 0)

    f32x4 acc[8][4];
    short8 af[4][2], b0[2][2], b1[2][2];

    // LDS fragment reads (swizzled)
    #define LOAD_A(mh) do { \
        const unsigned short* _p = Asb + (wm * 128 + (mh) * 64 + lm) * BK; \
        _Pragma("unroll") \
        for (int ii = 0; ii < 4; ++ii) { \
            af[ii][0] = *(const short8*)(_p + ii * 16 * BK + cx0); \
            af[ii][1] = *(const short8*)(_p + ii * 16 * BK + cx1); \
        } } while (0)
    #define LOAD_Bx(nh, dst) do { \
        const unsigned short* _p = Bsb + (wn * 64 + (nh) * 32 + lm) * BK; \
        _Pragma("unroll") \
        for (int jj = 0; jj < 2; ++jj) { \
            dst[jj][0] = *(const short8*)(_p + jj * 16 * BK + cx0); \
            dst[jj][1] = *(const short8*)(_p + jj * 16 * BK + cx1); \
        } } while (0)

    #define MFMA_HALF(mh) do { \
        __builtin_amdgcn_s_setprio(1); \
        _Pragma("unroll") \
        for (int ii = 0; ii < 4; ++ii) \
        _Pragma("unroll") \
        for (int jj = 0; jj < 2; ++jj) { \
            acc[(mh)*4+ii][jj]   = __builtin_amdgcn_mfma_f32_16x16x32_bf16( \
                af[ii][0], b0[jj][0], acc[(mh)*4+ii][jj], 0, 0, 0); \
            acc[(mh)*4+ii][jj]   = __builtin_amdgcn_mfma_f32_16x16x32_bf16( \
                af[ii][1], b0[jj][1], acc[(mh)*4+ii][jj], 0, 0, 0); \
            acc[(mh)*4+ii][2+jj] = __builtin_amdgcn_mfma_f32_16x16x32_bf16( \
                af[ii][0], b1[jj][0], acc[(mh)*4+ii][2+jj], 0, 0, 0); \
            acc[(mh)*4+ii][2+jj] = __builtin_amdgcn_mfma_f32_16x16x32_bf16( \
                af[ii][1], b1[jj][1], acc[(mh)*4+ii][2+jj], 0, 0, 0); \
        } \
        __builtin_amdgcn_s_setprio(0); } while (0)

    const int NT = K / BK;   // 8 (even: every tile's kt0 lands in buffer 0)

    // prologue: stage first tile's kt0 into buffer 0, ledger order A0,B0,B1,A1
    COMPUTE_BASES(sid0);
    GL(sA00, As, dA00); GL(sA01, As, dA01);
    GL(sB00, Bs, dB00); GL(sB01, Bs, dB01);
    GL(sB10, Bs, dB10); GL(sB11, Bs, dB11);
    GL(sA10, As, dA10); GL(sA11, As, dA11);

    for (int tix = sid0; tix < ntiles; tix += PGRID) {
        const int row0 = (tix / NCT) * BM;
        const int col0 = (tix % NCT) * BN;
#pragma unroll
        for (int i = 0; i < 8; ++i)
#pragma unroll
            for (int j = 0; j < 4; ++j) acc[i][j] = (f32x4){0.f, 0.f, 0.f, 0.f};

        for (int kt = 0; kt < NT; ++kt) {
            const int bc = (kt & 1) * LDT;
            const int bb = bc ^ LDT;
            const unsigned short* Asb = As + bc;
            const unsigned short* Bsb = Bs + bc;
            int hn = 1, ko = 0;
            if (kt + 1 < NT)               ko = (kt + 1) * BK;
            else if (tix + PGRID < ntiles) COMPUTE_BASES(tix + PGRID);  // ko = 0
            else                           hn = 0;

            // ---- P0 ----
            asm volatile("s_waitcnt vmcnt(2)" ::: "memory");
            __builtin_amdgcn_s_barrier();
            if (hn) {
                GL(sA00 + ko, As, bb + dA00); GL(sA01 + ko, As, bb + dA01);
                GL(sB00 + ko, Bs, bb + dB00); GL(sB01 + ko, Bs, bb + dB01);
            }
            LOAD_A(0);
            LOAD_Bx(0, b0);
            LOAD_Bx(1, b1);
            MFMA_HALF(0);

            // ---- P1 ----
            if (hn) { asm volatile("s_waitcnt vmcnt(4)" ::: "memory"); }
            else    { asm volatile("s_waitcnt vmcnt(0)" ::: "memory"); }
            __builtin_amdgcn_s_barrier();
            if (hn) {
                GL(sB10 + ko, Bs, bb + dB10); GL(sB11 + ko, Bs, bb + dB11);
                GL(sA10 + ko, As, bb + dA10); GL(sA11 + ko, As, bb + dA11);
            }
            LOAD_A(1);
            MFMA_HALF(1);
        }

        // epilogue: D row = lq*4 + reg, col = lane&15. col0 is 256-aligned so
        // the fp8/bf16 split (at NC/2) is block-uniform.
        const int qr = lq * 4;
        const bool lo_half = SPLIT && (col0 < NC / 2);
        const int cadj = SPLIT ? NC / 2 : 0;
#pragma unroll
        for (int i = 0; i < 8; ++i) {
#pragma unroll
            for (int r = 0; r < 4; ++r) {
                int gr = row0 + wm * 128 + i * 16 + qr + r;
                if (gr >= M) continue;
#pragma unroll
                for (int j = 0; j < 4; ++j) {
                    int gc = col0 + wn * 64 + j * 16 + lm;
                    float v = acc[i][j][r];
                    if (SPLIT && lo_half) {
                        int p = __builtin_amdgcn_cvt_pk_fp8_f32(v, v, 0, 0);
                        C8[(size_t)gr * (NC / 2) + gc] = (unsigned char)p;
                    } else {
                        C16[(size_t)gr * (NC - cadj) + (gc - cadj)] = f2bf(v);
                    }
                }
            }
        }
        // drain stores (and let next-tile kt0 loads, issued pre-epilogue, land)
        asm volatile("s_waitcnt vmcnt(0)" ::: "memory");
    }
    #undef LOAD_A
    #undef LOAD_Bx
    #undef MFMA_HALF
    #undef GL
    #undef COMPUTE_BASES
}

// ---------------------------------------------------------------------------
// Layer-1 fused epilogue: h[i] = relu( mean_j C8[j] + C16r[i] + b1 ), bf16 out.
// C8: y_l rows, 512 fp8 = 64 uint2. C16r: y_r rows, 512 bf16 = 64 uint4.
__global__ void k_agg_relu(const unsigned char* __restrict__ C8,
                           const unsigned short* __restrict__ C16r,
                           const int* __restrict__ rowptr, const int* __restrict__ col,
                           const float* __restrict__ b1, unsigned short* __restrict__ H, int n) {
    int node = blockIdx.x * (blockDim.x >> 6) + (threadIdx.x >> 6);
    int lane = threadIdx.x & 63;
    if (node >= n) return;
    int beg = rowptr[node], end = rowptr[node + 1];
    float acc[8] = {};
    const uint2* Cv = (const uint2*)C8;   // row stride 64 uint2
    int e = beg;
    for (; e + 4 <= end; e += 4) {
        int c0 = col[e], c1 = col[e + 1], c2 = col[e + 2], c3 = col[e + 3];
        uint2 v0 = Cv[(size_t)c0 * 64 + lane];
        uint2 v1 = Cv[(size_t)c1 * 64 + lane];
        uint2 v2 = Cv[(size_t)c2 * 64 + lane];
        uint2 v3 = Cv[(size_t)c3 * 64 + lane];
        unsigned int ws[8] = {v0.x, v0.y, v1.x, v1.y, v2.x, v2.y, v3.x, v3.y};
#pragma unroll
        for (int qq = 0; qq < 8; ++qq) {
            floatx2 flo = __builtin_amdgcn_cvt_pk_f32_fp8(ws[qq], 0);
            floatx2 fhi = __builtin_amdgcn_cvt_pk_f32_fp8(ws[qq], 1);
            int base = (qq & 1) * 4;
            acc[base + 0] += flo.x; acc[base + 1] += flo.y;
            acc[base + 2] += fhi.x; acc[base + 3] += fhi.y;
        }
    }
    for (; e < end; ++e) {
        uint2 v = Cv[(size_t)col[e] * 64 + lane];
        floatx2 f0 = __builtin_amdgcn_cvt_pk_f32_fp8(v.x, 0);
        floatx2 f1 = __builtin_amdgcn_cvt_pk_f32_fp8(v.x, 1);
        floatx2 f2 = __builtin_amdgcn_cvt_pk_f32_fp8(v.y, 0);
        floatx2 f3 = __builtin_amdgcn_cvt_pk_f32_fp8(v.y, 1);
        acc[0] += f0.x; acc[1] += f0.y; acc[2] += f1.x; acc[3] += f1.y;
        acc[4] += f2.x; acc[5] += f2.y; acc[6] += f3.x; acc[7] += f3.y;
    }
    float inv = 1.0f / fmaxf((float)(end - beg), 1.0f);
    uint4 yr = ((const uint4*)C16r)[(size_t)node * 64 + lane];
    unsigned int wr[4] = {yr.x, yr.y, yr.z, yr.w};
    float4 bv0 = ((const float4*)b1)[2 * lane];
    float4 bv1 = ((const float4*)b1)[2 * lane + 1];
    float bb[8] = {bv0.x, bv0.y, bv0.z, bv0.w, bv1.x, bv1.y, bv1.z, bv1.w};
    unsigned int r[4];
#pragma unroll
    for (int qq = 0; qq < 4; ++qq) {
        float v0 = fmaxf(acc[2 * qq] * inv     + bflo(wr[qq]) + bb[2 * qq],     0.f);
        float v1 = fmaxf(acc[2 * qq + 1] * inv + bfhi(wr[qq]) + bb[2 * qq + 1], 0.f);
        r[qq] = (unsigned)f2bf(v0) | ((unsigned)f2bf(v1) << 16);
    }
    uint4 o; o.x = r[0]; o.y = r[1]; o.z = r[2]; o.w = r[3];
    ((uint4*)H)[(size_t)node * 64 + lane] = o;
}

// ---------------------------------------------------------------------------
// Layer-2 fused epilogue: out[i] = log_softmax( mean_j C8[j] + C16r[i] + b2 ).
// C8: y_l rows, 256 fp8 = 64 uint (lane covers dims 4*lane..4*lane+3).
// C16r: y_r rows, 256 bf16 = 64 uint2. Output fp32.
__global__ void k_agg_lsm(const unsigned char* __restrict__ C8,
                          const unsigned short* __restrict__ C16r,
                          const int* __restrict__ rowptr, const int* __restrict__ col,
                          const float* __restrict__ b2, float* __restrict__ O, int n) {
    int node = blockIdx.x * (blockDim.x >> 6) + (threadIdx.x >> 6);
    int lane = threadIdx.x & 63;
    if (node >= n) return;
    int beg = rowptr[node], end = rowptr[node + 1];
    float acc[4] = {};
    const unsigned int* Cv = (const unsigned int*)C8;   // row stride 64 uint
    int e = beg;
    for (; e + 4 <= end; e += 4) {
        int c0 = col[e], c1 = col[e + 1], c2 = col[e + 2], c3 = col[e + 3];
        unsigned int u0 = Cv[(size_t)c0 * 64 + lane];
        unsigned int u1 = Cv[(size_t)c1 * 64 + lane];
        unsigned int u2 = Cv[(size_t)c2 * 64 + lane];
        unsigned int u3 = Cv[(size_t)c3 * 64 + lane];
        unsigned int us[4] = {u0, u1, u2, u3};
#pragma unroll
        for (int qq = 0; qq < 4; ++qq) {
            floatx2 flo = __builtin_amdgcn_cvt_pk_f32_fp8(us[qq], 0);
            floatx2 fhi = __builtin_amdgcn_cvt_pk_f32_fp8(us[qq], 1);
            acc[0] += flo.x; acc[1] += flo.y; acc[2] += fhi.x; acc[3] += fhi.y;
        }
    }
    for (; e < end; ++e) {
        unsigned int u = Cv[(size_t)col[e] * 64 + lane];
        floatx2 flo = __builtin_amdgcn_cvt_pk_f32_fp8(u, 0);
        floatx2 fhi = __builtin_amdgcn_cvt_pk_f32_fp8(u, 1);
        acc[0] += flo.x; acc[1] += flo.y; acc[2] += fhi.x; acc[3] += fhi.y;
    }
    float inv = 1.0f / fmaxf((float)(end - beg), 1.0f);
    uint2 yr = ((const uint2*)C16r)[(size_t)node * 64 + lane];
    float4 bv = ((const float4*)b2)[lane];
    float val[4];
    val[0] = acc[0] * inv + bflo(yr.x) + bv.x;
    val[1] = acc[1] * inv + bfhi(yr.x) + bv.y;
    val[2] = acc[2] * inv + bflo(yr.y) + bv.z;
    val[3] = acc[3] * inv + bfhi(yr.y) + bv.w;
    float mx = fmaxf(fmaxf(val[0], val[1]), fmaxf(val[2], val[3]));
#pragma unroll
    for (int off = 32; off > 0; off >>= 1) mx = fmaxf(mx, __shfl_xor(mx, off));
    float s = expf(val[0] - mx) + expf(val[1] - mx) + expf(val[2] - mx) + expf(val[3] - mx);
#pragma unroll
    for (int off = 32; off > 0; off >>= 1) s += __shfl_xor(s, off);
    float lse = mx + logf(s);
    float4 o = make_float4(val[0] - lse, val[1] - lse, val[2] - lse, val[3] - lse);
    ((float4*)O)[(size_t)node * 64 + lane] = o;
}

// ---------------------------------------------------------------------------
extern "C" void kernel_launch(void* const* d_in, const int* in_sizes, int n_in,
                              void* d_out, int out_size, void* d_ws, size_t ws_size,
                              hipStream_t stream) {
    const float* x   = (const float*)d_in[0];
    const int*   ei1 = (const int*)d_in[1];
    const int*   ei2 = (const int*)d_in[2];
    const float* W1l = (const float*)d_in[3];
    const float* b1  = (const float*)d_in[4];
    const float* W1r = (const float*)d_in[5];
    const float* W2l = (const float*)d_in[6];
    const float* b2  = (const float*)d_in[7];
    const float* W2r = (const float*)d_in[8];
    float* out = (float*)d_out;

    const int N  = in_sizes[0] / DIN;
    const int E1 = in_sizes[1] / 2;
    const int E2 = in_sizes[2] / 2;
    const int Emax = (E1 > E2) ? E1 : E2;
    const int NB = (N + SCAN_B - 1) / SCAN_B;

    // Workspace layout
    unsigned short* x_bf  = (unsigned short*)d_ws;             // N*512 bf16
    unsigned short* h_bf  = x_bf + (size_t)N * 512;            // N*512 bf16
    unsigned char*  c1l   = (unsigned char*)(h_bf + (size_t)N * 512);  // N*512 fp8
    unsigned short* c1r   = (unsigned short*)(c1l + (size_t)N * 512);  // N*512 bf16
    // layer-2 C buffers alias the (dead-by-then) c1 region
    unsigned char*  c2l   = c1l;                               // N*256 fp8
    unsigned short* c2r   = (unsigned short*)(c2l + (size_t)N * 256);  // N*256 bf16
    unsigned short* w1_bf = c1r + (size_t)N * 512;             // 1024*512
    unsigned short* w2_bf = w1_bf + 1024 * 512;                // 512*512
    int* rowptr1 = (int*)(w2_bf + 512 * 512);                  // N+1
    int* rowptr2 = rowptr1 + (N + 1);                          // N+1
    int* cursor1 = rowptr2 + (N + 1);                          // N
    int* cursor2 = cursor1 + N;                                // N
    int* deg1    = cursor2 + N;                                // N
    int* deg2    = deg1 + N;                                   // N
    int* part1   = deg2 + N;                                   // 256
    int* part2   = part1 + 256;                                // 256
    int* col1    = part2 + 256;                                // E1
    int* col2    = col1 + E1;                                  // E2
    (void)ws_size; (void)n_in; (void)out_size;

    // conversions
    {
        int n8 = N * 512 / 8;
        k_f2bf<<<(n8 + 255) / 256, 256, 0, stream>>>(x, x_bf, n8);
        k_wcvt<<<(98304 + 255) / 256, 256, 0, stream>>>(W1l, W1r, W2l, W2r, w1_bf, w2_bf);
    }

    // both CSRs, batched
    hipMemsetAsync(deg1, 0, (size_t)2 * N * sizeof(int), stream);
    {
        dim3 ge((Emax + 255) / 256, 2);
        k_count2<<<ge, 256, 0, stream>>>(ei1 + E1, ei2 + E2, deg1, deg2, E1, E2);
        k_scan_partial2<<<dim3(NB, 2), SCAN_B, 0, stream>>>(deg1, deg2, part1, part2, N);
        k_scan_part2b<<<2, SCAN_B, 0, stream>>>(part1, part2, NB, rowptr1, rowptr2, N);
        k_scan_final2<<<dim3(NB, 2), SCAN_B, 0, stream>>>(deg1, deg2, part1, part2,
                                                          rowptr1, rowptr2, cursor1, cursor2, N);
        k_fill2<<<ge, 256, 0, stream>>>(ei1, ei1 + E1, ei2, ei2 + E2,
                                        cursor1, cursor2, col1, col2, E1, E2);
    }

    const int RT = (N + BM - 1) / BM;            // 196 row tiles

    // Layer 1: [y_l|y_r] = x @ [W1l;W1r]^T; y_l -> fp8, y_r -> bf16.
    k_gemm_p2<4, 1><<<PGRID, 512, 0, stream>>>(x_bf, w1_bf, c1l, c1r, N, DIN, 1024, RT * 4);
    k_agg_relu<<<(N + 3) / 4, 256, 0, stream>>>(c1l, c1r, rowptr1, col1, b1, h_bf, N);

    // Layer 2: [y_l|y_r] = h @ [W2l;W2r]^T; y_l -> fp8, y_r -> bf16.
    k_gemm_p2<2, 1><<<PGRID, 512, 0, stream>>>(h_bf, w2_bf, c2l, c2r, N, DHID, 512, RT * 2);
    k_agg_lsm<<<(N + 3) / 4, 256, 0, stream>>>(c2l, c2r, rowptr2, col2, b2, out, N);
}

// Round 6
// 480.086 us; speedup vs baseline: 1.1066x; 1.1066x over previous
//
#include <hip/hip_runtime.h>
#include <math.h>

#define DIN  512
#define DHID 512
#define DOUT 256

typedef __attribute__((ext_vector_type(8))) short short8;
typedef __attribute__((ext_vector_type(4))) float f32x4;
typedef __attribute__((ext_vector_type(2))) float floatx2;

__device__ __forceinline__ unsigned short f2bf(float f) {
    unsigned int u = __float_as_uint(f);
    u += 0x7fffu + ((u >> 16) & 1u);
    return (unsigned short)(u >> 16);
}
__device__ __forceinline__ float bflo(unsigned int w) { return __uint_as_float(w << 16); }
__device__ __forceinline__ float bfhi(unsigned int w) { return __uint_as_float(w & 0xffff0000u); }

// ---------------------------------------------------------------------------
// fp32 -> bf16, 8 elems per index i
__device__ __forceinline__ void cvt8(const float* __restrict__ in,
                                     unsigned short* __restrict__ out, int i) {
    const float4* iv = (const float4*)in;
    float4 a = iv[2 * i], b = iv[2 * i + 1];
    uint4 o;
    o.x = (unsigned)f2bf(a.x) | ((unsigned)f2bf(a.y) << 16);
    o.y = (unsigned)f2bf(a.z) | ((unsigned)f2bf(a.w) << 16);
    o.z = (unsigned)f2bf(b.x) | ((unsigned)f2bf(b.y) << 16);
    o.w = (unsigned)f2bf(b.z) | ((unsigned)f2bf(b.w) << 16);
    ((uint4*)out)[i] = o;
}

// Fused prep: x->bf16, all four W->bf16, and deg[0..ndeg) = 0 (replaces
// k_f2bf + k_wcvt + hipMemsetAsync: -2 launches).
__global__ void k_prep(const float* __restrict__ x, unsigned short* __restrict__ x_bf,
                       const float* __restrict__ W1l, const float* __restrict__ W1r,
                       const float* __restrict__ W2l, const float* __restrict__ W2r,
                       unsigned short* __restrict__ w1, unsigned short* __restrict__ w2,
                       int* __restrict__ deg, int n8, int ndeg) {
    int i = blockIdx.x * blockDim.x + threadIdx.x;
    if (i < n8) { cvt8(x, x_bf, i); return; }
    i -= n8;
    if (i < 32768)  { cvt8(W1l, w1, i); return; }
    if (i < 65536)  { cvt8(W1r, w1 + 262144, i - 32768); return; }
    if (i < 81920)  { cvt8(W2l, w2, i - 65536); return; }
    if (i < 98304)  { cvt8(W2r, w2 + 131072, i - 81920); return; }
    i -= 98304;
    if (i < ndeg) deg[i] = 0;
}

// ---------------------------------------------------------------------------
// CSR build, both layers batched (blockIdx.y = layer)
__global__ void k_count2(const int* __restrict__ d1, const int* __restrict__ d2,
                         int* __restrict__ deg1, int* __restrict__ deg2, int E1, int E2) {
    int e = blockIdx.x * blockDim.x + threadIdx.x;
    if (blockIdx.y == 0) { if (e < E1) atomicAdd(&deg1[d1[e]], 1); }
    else                 { if (e < E2) atomicAdd(&deg2[d2[e]], 1); }
}

#define SCAN_B 256
__global__ void k_scan_partial2(const int* __restrict__ deg1, const int* __restrict__ deg2,
                                int* __restrict__ part1, int* __restrict__ part2, int n) {
    __shared__ int s[SCAN_B];
    const int* deg = blockIdx.y ? deg2 : deg1;
    int* part      = blockIdx.y ? part2 : part1;
    int i = blockIdx.x * SCAN_B + threadIdx.x;
    s[threadIdx.x] = (i < n) ? deg[i] : 0;
    __syncthreads();
    for (int off = SCAN_B / 2; off > 0; off >>= 1) {
        if (threadIdx.x < off) s[threadIdx.x] += s[threadIdx.x + off];
        __syncthreads();
    }
    if (threadIdx.x == 0) part[blockIdx.x] = s[0];
}

__global__ void k_scan_part2b(int* __restrict__ part1, int* __restrict__ part2, int nb,
                              int* __restrict__ rowptr1, int* __restrict__ rowptr2, int n) {
    __shared__ int s[SCAN_B];
    int* part   = blockIdx.x ? part2 : part1;
    int* rowptr = blockIdx.x ? rowptr2 : rowptr1;
    int v = (threadIdx.x < nb) ? part[threadIdx.x] : 0;
    s[threadIdx.x] = v;
    __syncthreads();
    for (int off = 1; off < SCAN_B; off <<= 1) {
        int t = (threadIdx.x >= off) ? s[threadIdx.x - off] : 0;
        __syncthreads();
        s[threadIdx.x] += t;
        __syncthreads();
    }
    if (threadIdx.x < nb) part[threadIdx.x] = s[threadIdx.x] - v;  // exclusive
    if (threadIdx.x == SCAN_B - 1) rowptr[n] = s[SCAN_B - 1];
}

__global__ void k_scan_final2(const int* __restrict__ deg1, const int* __restrict__ deg2,
                              const int* __restrict__ part1, const int* __restrict__ part2,
                              int* __restrict__ rowptr1, int* __restrict__ rowptr2,
                              int* __restrict__ cursor1, int* __restrict__ cursor2, int n) {
    __shared__ int s[SCAN_B];
    const int* deg  = blockIdx.y ? deg2 : deg1;
    const int* part = blockIdx.y ? part2 : part1;
    int* rowptr     = blockIdx.y ? rowptr2 : rowptr1;
    int* cursor     = blockIdx.y ? cursor2 : cursor1;
    int i = blockIdx.x * SCAN_B + threadIdx.x;
    int v = (i < n) ? deg[i] : 0;
    s[threadIdx.x] = v;
    __syncthreads();
    for (int off = 1; off < SCAN_B; off <<= 1) {
        int t = (threadIdx.x >= off) ? s[threadIdx.x - off] : 0;
        __syncthreads();
        s[threadIdx.x] += t;
        __syncthreads();
    }
    if (i < n) {
        int ex = part[blockIdx.x] + s[threadIdx.x] - v;
        rowptr[i] = ex;
        cursor[i] = ex;
    }
}

__global__ void k_fill2(const int* __restrict__ s1, const int* __restrict__ d1,
                        const int* __restrict__ s2, const int* __restrict__ d2,
                        int* __restrict__ cur1, int* __restrict__ cur2,
                        int* __restrict__ col1, int* __restrict__ col2, int E1, int E2) {
    int e = blockIdx.x * blockDim.x + threadIdx.x;
    if (blockIdx.y == 0) {
        if (e < E1) { int p = atomicAdd(&cur1[d1[e]], 1); col1[p] = s1[e]; }
    } else {
        if (e < E2) { int p = atomicAdd(&cur2[d2[e]], 1); col2[p] = s2[e]; }
    }
}

// ---------------------------------------------------------------------------
// bf16 MFMA GEMM: out = A @ W^T. SPLIT=1: columns [0,NC/2) -> fp8 e4m3 C8,
// columns [NC/2,NC) -> bf16 C16 (stride NC/2 each). SPLIT=0: all bf16.
// LDS layout is XOR-swizzled: row R's k-chunk q (16B) lives at slot
// q ^ ((R>>1)&3) — spreads fragment reads over all 8 bank groups (2
// lanes/bank = free). Staging stays lane-contiguous in LDS (global_load_lds
// requirement); only WHICH global chunk a thread fetches changes.
// [round-0 verified kernel: 82.8 us L1 @ MfmaUtil 26.6%, 0 bank conflicts.
//  VGPR 56 + 64 AGPR ~= 120 unified -> 4 waves/SIMD; occupancy cap 50%.]
#define TM 128
#define TN 128
#define TK 32

template <int NCT, int SPLIT>
__global__ __launch_bounds__(256, 4)
void k_gemm_mfma(const unsigned short* __restrict__ A, const unsigned short* __restrict__ W,
                 unsigned char* __restrict__ C8, unsigned short* __restrict__ C16,
                 int M, int K, int NC) {
    __shared__ __align__(16) unsigned short As[TM * TK];
    __shared__ __align__(16) unsigned short Bs[TN * TK];
    const int id = blockIdx.x;
    const int xcd = id & 7;
    const int s = id >> 3;
    const int row0 = ((s / NCT) * 8 + xcd) * TM;
    const int col0 = (s % NCT) * TN;
    if (row0 >= M) return;

    const int t = threadIdx.x;
    const int lane = t & 63;
    const int w = t >> 6;
    const int wr = (w >> 1) * 64;
    const int wc = (w & 1) * 64;
    const int lm = lane & 15;
    const int q = lane >> 4;             // logical k-chunk 0..3 (8 bf16 each)

    f32x4 acc[4][4];
#pragma unroll
    for (int i = 0; i < 4; ++i)
#pragma unroll
        for (int j = 0; j < 4; ++j) acc[i][j] = (f32x4){0.f, 0.f, 0.f, 0.f};

    // staging: LDS slot t holds row ar=t>>2, slot-chunk c=t&3; that slot must
    // receive global chunk s = c ^ ((row>>1)&3) = (t&3) ^ ((t>>3)&3).
    // Rows ar+64 (slot t+256) have the same XOR term (64 rows = +32 pairs).
    const int ar = t >> 2;
    const int as = (((t & 3) ^ ((t >> 3) & 3))) * 8;

    for (int k0 = 0; k0 < K; k0 += TK) {
        int r1 = row0 + ar;      if (r1 >= M) r1 = M - 1;
        int r2 = row0 + ar + 64; if (r2 >= M) r2 = M - 1;
        const unsigned short* ga1 = A + (size_t)r1 * K + k0 + as;
        const unsigned short* ga2 = A + (size_t)r2 * K + k0 + as;
        const unsigned short* gb1 = W + (size_t)(col0 + ar) * K + k0 + as;
        const unsigned short* gb2 = W + (size_t)(col0 + ar + 64) * K + k0 + as;
        __builtin_amdgcn_global_load_lds(
            (const __attribute__((address_space(1))) unsigned int*)ga1,
            (__attribute__((address_space(3))) unsigned int*)&As[t * 8], 16, 0, 0);
        __builtin_amdgcn_global_load_lds(
            (const __attribute__((address_space(1))) unsigned int*)ga2,
            (__attribute__((address_space(3))) unsigned int*)&As[(t + 256) * 8], 16, 0, 0);
        __builtin_amdgcn_global_load_lds(
            (const __attribute__((address_space(1))) unsigned int*)gb1,
            (__attribute__((address_space(3))) unsigned int*)&Bs[t * 8], 16, 0, 0);
        __builtin_amdgcn_global_load_lds(
            (const __attribute__((address_space(1))) unsigned int*)gb2,
            (__attribute__((address_space(3))) unsigned int*)&Bs[(t + 256) * 8], 16, 0, 0);
        __syncthreads();

        short8 a[4], b[4];
#pragma unroll
        for (int i = 0; i < 4; ++i) {
            int R = wr + i * 16 + lm;
            a[i] = *(const short8*)&As[R * TK + ((q ^ ((R >> 1) & 3)) * 8)];
        }
#pragma unroll
        for (int j = 0; j < 4; ++j) {
            int R = wc + j * 16 + lm;
            b[j] = *(const short8*)&Bs[R * TK + ((q ^ ((R >> 1) & 3)) * 8)];
        }
#pragma unroll
        for (int i = 0; i < 4; ++i)
#pragma unroll
            for (int j = 0; j < 4; ++j)
                acc[i][j] = __builtin_amdgcn_mfma_f32_16x16x32_bf16(a[i], b[j], acc[i][j], 0, 0, 0);
        __syncthreads();
    }

    // epilogue: D row = quad*4 + reg, col = lane&15. col0 is 128-aligned so
    // the fp8/bf16 split (at NC/2) is block-uniform.
    const int qr = (lane >> 4) * 4;
    const bool lo_half = SPLIT && (col0 < NC / 2);
    const int cadj = SPLIT ? NC / 2 : 0;
#pragma unroll
    for (int i = 0; i < 4; ++i) {
#pragma unroll
        for (int r = 0; r < 4; ++r) {
            int gr = row0 + wr + i * 16 + qr + r;
            if (gr >= M) continue;
#pragma unroll
            for (int j = 0; j < 4; ++j) {
                int gc = col0 + wc + j * 16 + lm;
                float v = acc[i][j][r];
                if (SPLIT && lo_half) {
                    int p = __builtin_amdgcn_cvt_pk_fp8_f32(v, v, 0, 0);
                    C8[(size_t)gr * (NC / 2) + gc] = (unsigned char)p;
                } else {
                    C16[(size_t)gr * (NC - cadj) + (gc - cadj)] = f2bf(v);
                }
            }
        }
    }
}

// ---------------------------------------------------------------------------
// Layer-1 fused epilogue: h[i] = relu( mean_j C8[j] + C16r[i] + b1 ), bf16 out.
// C8: y_l rows, 512 fp8 = 64 uint2. C16r: y_r rows, 512 bf16 = 64 uint4.
__global__ void k_agg_relu(const unsigned char* __restrict__ C8,
                           const unsigned short* __restrict__ C16r,
                           const int* __restrict__ rowptr, const int* __restrict__ col,
                           const float* __restrict__ b1, unsigned short* __restrict__ H, int n) {
    int node = blockIdx.x * (blockDim.x >> 6) + (threadIdx.x >> 6);
    int lane = threadIdx.x & 63;
    if (node >= n) return;
    int beg = rowptr[node], end = rowptr[node + 1];
    float acc[8] = {};
    const uint2* Cv = (const uint2*)C8;   // row stride 64 uint2
    int e = beg;
    for (; e + 4 <= end; e += 4) {
        int c0 = col[e], c1 = col[e + 1], c2 = col[e + 2], c3 = col[e + 3];
        uint2 v0 = Cv[(size_t)c0 * 64 + lane];
        uint2 v1 = Cv[(size_t)c1 * 64 + lane];
        uint2 v2 = Cv[(size_t)c2 * 64 + lane];
        uint2 v3 = Cv[(size_t)c3 * 64 + lane];
        unsigned int ws[8] = {v0.x, v0.y, v1.x, v1.y, v2.x, v2.y, v3.x, v3.y};
#pragma unroll
        for (int qq = 0; qq < 8; ++qq) {
            floatx2 flo = __builtin_amdgcn_cvt_pk_f32_fp8(ws[qq], 0);
            floatx2 fhi = __builtin_amdgcn_cvt_pk_f32_fp8(ws[qq], 1);
            int base = (qq & 1) * 4;
            acc[base + 0] += flo.x; acc[base + 1] += flo.y;
            acc[base + 2] += fhi.x; acc[base + 3] += fhi.y;
        }
    }
    for (; e < end; ++e) {
        uint2 v = Cv[(size_t)col[e] * 64 + lane];
        floatx2 f0 = __builtin_amdgcn_cvt_pk_f32_fp8(v.x, 0);
        floatx2 f1 = __builtin_amdgcn_cvt_pk_f32_fp8(v.x, 1);
        floatx2 f2 = __builtin_amdgcn_cvt_pk_f32_fp8(v.y, 0);
        floatx2 f3 = __builtin_amdgcn_cvt_pk_f32_fp8(v.y, 1);
        acc[0] += f0.x; acc[1] += f0.y; acc[2] += f1.x; acc[3] += f1.y;
        acc[4] += f2.x; acc[5] += f2.y; acc[6] += f3.x; acc[7] += f3.y;
    }
    float inv = 1.0f / fmaxf((float)(end - beg), 1.0f);
    uint4 yr = ((const uint4*)C16r)[(size_t)node * 64 + lane];
    unsigned int wr[4] = {yr.x, yr.y, yr.z, yr.w};
    float4 bv0 = ((const float4*)b1)[2 * lane];
    float4 bv1 = ((const float4*)b1)[2 * lane + 1];
    float bb[8] = {bv0.x, bv0.y, bv0.z, bv0.w, bv1.x, bv1.y, bv1.z, bv1.w};
    unsigned int r[4];
#pragma unroll
    for (int qq = 0; qq < 4; ++qq) {
        float v0 = fmaxf(acc[2 * qq] * inv     + bflo(wr[qq]) + bb[2 * qq],     0.f);
        float v1 = fmaxf(acc[2 * qq + 1] * inv + bfhi(wr[qq]) + bb[2 * qq + 1], 0.f);
        r[qq] = (unsigned)f2bf(v0) | ((unsigned)f2bf(v1) << 16);
    }
    uint4 o; o.x = r[0]; o.y = r[1]; o.z = r[2]; o.w = r[3];
    ((uint4*)H)[(size_t)node * 64 + lane] = o;
}

// ---------------------------------------------------------------------------
// Layer-2 fused epilogue: out[i] = log_softmax( mean_j C8[j] + C16r[i] + b2 ).
// C8: y_l rows, 256 fp8 = 64 uint (lane covers dims 4*lane..4*lane+3).
// C16r: y_r rows, 256 bf16 = 64 uint2. Output fp32.
__global__ void k_agg_lsm(const unsigned char* __restrict__ C8,
                          const unsigned short* __restrict__ C16r,
                          const int* __restrict__ rowptr, const int* __restrict__ col,
                          const float* __restrict__ b2, float* __restrict__ O, int n) {
    int node = blockIdx.x * (blockDim.x >> 6) + (threadIdx.x >> 6);
    int lane = threadIdx.x & 63;
    if (node >= n) return;
    int beg = rowptr[node], end = rowptr[node + 1];
    float acc[4] = {};
    const unsigned int* Cv = (const unsigned int*)C8;   // row stride 64 uint
    int e = beg;
    for (; e + 4 <= end; e += 4) {
        int c0 = col[e], c1 = col[e + 1], c2 = col[e + 2], c3 = col[e + 3];
        unsigned int u0 = Cv[(size_t)c0 * 64 + lane];
        unsigned int u1 = Cv[(size_t)c1 * 64 + lane];
        unsigned int u2 = Cv[(size_t)c2 * 64 + lane];
        unsigned int u3 = Cv[(size_t)c3 * 64 + lane];
        unsigned int us[4] = {u0, u1, u2, u3};
#pragma unroll
        for (int qq = 0; qq < 4; ++qq) {
            floatx2 flo = __builtin_amdgcn_cvt_pk_f32_fp8(us[qq], 0);
            floatx2 fhi = __builtin_amdgcn_cvt_pk_f32_fp8(us[qq], 1);
            acc[0] += flo.x; acc[1] += flo.y; acc[2] += fhi.x; acc[3] += fhi.y;
        }
    }
    for (; e < end; ++e) {
        unsigned int u = Cv[(size_t)col[e] * 64 + lane];
        floatx2 flo = __builtin_amdgcn_cvt_pk_f32_fp8(u, 0);
        floatx2 fhi = __builtin_amdgcn_cvt_pk_f32_fp8(u, 1);
        acc[0] += flo.x; acc[1] += flo.y; acc[2] += fhi.x; acc[3] += fhi.y;
    }
    float inv = 1.0f / fmaxf((float)(end - beg), 1.0f);
    uint2 yr = ((const uint2*)C16r)[(size_t)node * 64 + lane];
    float4 bv = ((const float4*)b2)[lane];
    float val[4];
    val[0] = acc[0] * inv + bflo(yr.x) + bv.x;
    val[1] = acc[1] * inv + bfhi(yr.x) + bv.y;
    val[2] = acc[2] * inv + bflo(yr.y) + bv.z;
    val[3] = acc[3] * inv + bfhi(yr.y) + bv.w;
    float mx = fmaxf(fmaxf(val[0], val[1]), fmaxf(val[2], val[3]));
#pragma unroll
    for (int off = 32; off > 0; off >>= 1) mx = fmaxf(mx, __shfl_xor(mx, off));
    float s = expf(val[0] - mx) + expf(val[1] - mx) + expf(val[2] - mx) + expf(val[3] - mx);
#pragma unroll
    for (int off = 32; off > 0; off >>= 1) s += __shfl_xor(s, off);
    float lse = mx + logf(s);
    float4 o = make_float4(val[0] - lse, val[1] - lse, val[2] - lse, val[3] - lse);
    ((float4*)O)[(size_t)node * 64 + lane] = o;
}

// ---------------------------------------------------------------------------
extern "C" void kernel_launch(void* const* d_in, const int* in_sizes, int n_in,
                              void* d_out, int out_size, void* d_ws, size_t ws_size,
                              hipStream_t stream) {
    const float* x   = (const float*)d_in[0];
    const int*   ei1 = (const int*)d_in[1];
    const int*   ei2 = (const int*)d_in[2];
    const float* W1l = (const float*)d_in[3];
    const float* b1  = (const float*)d_in[4];
    const float* W1r = (const float*)d_in[5];
    const float* W2l = (const float*)d_in[6];
    const float* b2  = (const float*)d_in[7];
    const float* W2r = (const float*)d_in[8];
    float* out = (float*)d_out;

    const int N  = in_sizes[0] / DIN;
    const int E1 = in_sizes[1] / 2;
    const int E2 = in_sizes[2] / 2;
    const int Emax = (E1 > E2) ? E1 : E2;
    const int NB = (N + SCAN_B - 1) / SCAN_B;

    // Workspace layout
    unsigned short* x_bf  = (unsigned short*)d_ws;             // N*512 bf16
    unsigned short* h_bf  = x_bf + (size_t)N * 512;            // N*512 bf16
    unsigned char*  c1l   = (unsigned char*)(h_bf + (size_t)N * 512);  // N*512 fp8
    unsigned short* c1r   = (unsigned short*)(c1l + (size_t)N * 512);  // N*512 bf16
    // layer-2 C buffers alias the (dead-by-then) c1 region
    unsigned char*  c2l   = c1l;                               // N*256 fp8
    unsigned short* c2r   = (unsigned short*)(c2l + (size_t)N * 256);  // N*256 bf16
    unsigned short* w1_bf = c1r + (size_t)N * 512;             // 1024*512
    unsigned short* w2_bf = w1_bf + 1024 * 512;                // 512*512
    int* rowptr1 = (int*)(w2_bf + 512 * 512);                  // N+1
    int* rowptr2 = rowptr1 + (N + 1);                          // N+1
    int* cursor1 = rowptr2 + (N + 1);                          // N
    int* cursor2 = cursor1 + N;                                // N
    int* deg1    = cursor2 + N;                                // N
    int* deg2    = deg1 + N;                                   // N
    int* part1   = deg2 + N;                                   // 256
    int* part2   = part1 + 256;                                // 256
    int* col1    = part2 + 256;                                // E1
    int* col2    = col1 + E1;                                  // E2
    (void)ws_size; (void)n_in; (void)out_size;

    // fused conversions + deg zeroing (deg1,deg2 are contiguous: 2N ints)
    {
        int n8 = N * 512 / 8;
        int tot = n8 + 98304 + 2 * N;
        k_prep<<<(tot + 255) / 256, 256, 0, stream>>>(x, x_bf, W1l, W1r, W2l, W2r,
                                                      w1_bf, w2_bf, deg1, n8, 2 * N);
    }

    // both CSRs, batched
    {
        dim3 ge((Emax + 255) / 256, 2);
        k_count2<<<ge, 256, 0, stream>>>(ei1 + E1, ei2 + E2, deg1, deg2, E1, E2);
        k_scan_partial2<<<dim3(NB, 2), SCAN_B, 0, stream>>>(deg1, deg2, part1, part2, N);
        k_scan_part2b<<<2, SCAN_B, 0, stream>>>(part1, part2, NB, rowptr1, rowptr2, N);
        k_scan_final2<<<dim3(NB, 2), SCAN_B, 0, stream>>>(deg1, deg2, part1, part2,
                                                          rowptr1, rowptr2, cursor1, cursor2, N);
        k_fill2<<<ge, 256, 0, stream>>>(ei1, ei1 + E1, ei2, ei2 + E2,
                                        cursor1, cursor2, col1, col2, E1, E2);
    }

    // Layer 1: [y_l|y_r] = x @ [W1l;W1r]^T; y_l -> fp8, y_r -> bf16.
    // Split into two row-range dispatches (~halves): lowers the rocprof top-5
    // visibility threshold from ~83us to ~42us so the largest non-GEMM
    // kernels surface with counters (diagnosis for the 73% non-GEMM budget).
    {
        const int M1 = 196 * TM;                 // 25088
        if (M1 < N) {
            const int G8a = (196 + 7) / 8;       // 25
            k_gemm_mfma<8, 1><<<G8a * 8 * 8, 256, 0, stream>>>(
                x_bf, w1_bf, c1l, c1r, M1, DIN, 1024);
            const int M2 = N - M1;
            const int MB2 = (M2 + TM - 1) / TM;
            const int G8b = (MB2 + 7) / 8;
            k_gemm_mfma<8, 1><<<G8b * 8 * 8, 256, 0, stream>>>(
                x_bf + (size_t)M1 * DIN, w1_bf,
                c1l + (size_t)M1 * 512, c1r + (size_t)M1 * 512, M2, DIN, 1024);
        } else {
            const int MB = (N + TM - 1) / TM;
            const int G8 = (MB + 7) / 8;
            k_gemm_mfma<8, 1><<<G8 * 8 * 8, 256, 0, stream>>>(
                x_bf, w1_bf, c1l, c1r, N, DIN, 1024);
        }
    }
    k_agg_relu<<<(N + 3) / 4, 256, 0, stream>>>(c1l, c1r, rowptr1, col1, b1, h_bf, N);

    // Layer 2: [y_l|y_r] = h @ [W2l;W2r]^T; y_l -> fp8, y_r -> bf16.
    {
        const int MB = (N + TM - 1) / TM;
        const int G8 = (MB + 7) / 8;
        k_gemm_mfma<4, 1><<<G8 * 8 * 4, 256, 0, stream>>>(
            h_bf, w2_bf, c2l, c2r, N, DHID, 512);
    }
    k_agg_lsm<<<(N + 3) / 4, 256, 0, stream>>>(c2l, c2r, rowptr2, col2, b2, out, N);
}

// Round 7
// 453.898 us; speedup vs baseline: 1.1704x; 1.0577x over previous
//
#include <hip/hip_runtime.h>
#include <math.h>

#define DIN  512
#define DHID 512
#define DOUT 256

typedef __attribute__((ext_vector_type(8))) short short8;
typedef __attribute__((ext_vector_type(4))) float f32x4;
typedef __attribute__((ext_vector_type(2))) float floatx2;

__device__ __forceinline__ unsigned short f2bf(float f) {
    unsigned int u = __float_as_uint(f);
    u += 0x7fffu + ((u >> 16) & 1u);
    return (unsigned short)(u >> 16);
}
__device__ __forceinline__ float bflo(unsigned int w) { return __uint_as_float(w << 16); }
__device__ __forceinline__ float bfhi(unsigned int w) { return __uint_as_float(w & 0xffff0000u); }

// ---------------------------------------------------------------------------
// fp32 -> bf16, 8 elems per index i
__device__ __forceinline__ void cvt8(const float* __restrict__ in,
                                     unsigned short* __restrict__ out, int i) {
    const float4* iv = (const float4*)in;
    float4 a = iv[2 * i], b = iv[2 * i + 1];
    uint4 o;
    o.x = (unsigned)f2bf(a.x) | ((unsigned)f2bf(a.y) << 16);
    o.y = (unsigned)f2bf(a.z) | ((unsigned)f2bf(a.w) << 16);
    o.z = (unsigned)f2bf(b.x) | ((unsigned)f2bf(b.y) << 16);
    o.w = (unsigned)f2bf(b.z) | ((unsigned)f2bf(b.w) << 16);
    ((uint4*)out)[i] = o;
}

// Fused prep + degree count: x->bf16, four W->bf16, then appended blocks do
// the per-edge degree atomics for BOTH layers (deg zeroed by memset before).
// count2 has no dependency on the conversions, so its blocks overlap them.
__global__ void k_prep_cnt(const float* __restrict__ x, unsigned short* __restrict__ x_bf,
                           const float* __restrict__ W1l, const float* __restrict__ W1r,
                           const float* __restrict__ W2l, const float* __restrict__ W2r,
                           unsigned short* __restrict__ w1, unsigned short* __restrict__ w2,
                           const int* __restrict__ d1, const int* __restrict__ d2,
                           int* __restrict__ deg1, int* __restrict__ deg2,
                           int n8, int E1, int E2, int EB) {
    int i = blockIdx.x * blockDim.x + threadIdx.x;
    if (i < n8) { cvt8(x, x_bf, i); return; }
    i -= n8;
    if (i < 32768)  { cvt8(W1l, w1, i); return; }
    if (i < 65536)  { cvt8(W1r, w1 + 262144, i - 32768); return; }
    if (i < 81920)  { cvt8(W2l, w2, i - 65536); return; }
    if (i < 98304)  { cvt8(W2r, w2 + 131072, i - 81920); return; }
    i -= 98304;
    if (i < EB * 256) { if (i < E1) atomicAdd(&deg1[d1[i]], 1); return; }
    i -= EB * 256;
    if (i < E2) atomicAdd(&deg2[d2[i]], 1);
}

#define SCAN_B 256
__global__ void k_scan_partial2(const int* __restrict__ deg1, const int* __restrict__ deg2,
                                int* __restrict__ part1, int* __restrict__ part2, int n) {
    __shared__ int s[SCAN_B];
    const int* deg = blockIdx.y ? deg2 : deg1;
    int* part      = blockIdx.y ? part2 : part1;
    int i = blockIdx.x * SCAN_B + threadIdx.x;
    s[threadIdx.x] = (i < n) ? deg[i] : 0;
    __syncthreads();
    for (int off = SCAN_B / 2; off > 0; off >>= 1) {
        if (threadIdx.x < off) s[threadIdx.x] += s[threadIdx.x + off];
        __syncthreads();
    }
    if (threadIdx.x == 0) part[blockIdx.x] = s[0];
}

__global__ void k_scan_part2b(int* __restrict__ part1, int* __restrict__ part2, int nb,
                              int* __restrict__ rowptr1, int* __restrict__ rowptr2, int n) {
    __shared__ int s[SCAN_B];
    int* part   = blockIdx.x ? part2 : part1;
    int* rowptr = blockIdx.x ? rowptr2 : rowptr1;
    int v = (threadIdx.x < nb) ? part[threadIdx.x] : 0;
    s[threadIdx.x] = v;
    __syncthreads();
    for (int off = 1; off < SCAN_B; off <<= 1) {
        int t = (threadIdx.x >= off) ? s[threadIdx.x - off] : 0;
        __syncthreads();
        s[threadIdx.x] += t;
        __syncthreads();
    }
    if (threadIdx.x < nb) part[threadIdx.x] = s[threadIdx.x] - v;  // exclusive
    if (threadIdx.x == SCAN_B - 1) rowptr[n] = s[SCAN_B - 1];
}

__global__ void k_scan_final2(const int* __restrict__ deg1, const int* __restrict__ deg2,
                              const int* __restrict__ part1, const int* __restrict__ part2,
                              int* __restrict__ rowptr1, int* __restrict__ rowptr2,
                              int* __restrict__ cursor1, int* __restrict__ cursor2, int n) {
    __shared__ int s[SCAN_B];
    const int* deg  = blockIdx.y ? deg2 : deg1;
    const int* part = blockIdx.y ? part2 : part1;
    int* rowptr     = blockIdx.y ? rowptr2 : rowptr1;
    int* cursor     = blockIdx.y ? cursor2 : cursor1;
    int i = blockIdx.x * SCAN_B + threadIdx.x;
    int v = (i < n) ? deg[i] : 0;
    s[threadIdx.x] = v;
    __syncthreads();
    for (int off = 1; off < SCAN_B; off <<= 1) {
        int t = (threadIdx.x >= off) ? s[threadIdx.x - off] : 0;
        __syncthreads();
        s[threadIdx.x] += t;
        __syncthreads();
    }
    if (i < n) {
        int ex = part[blockIdx.x] + s[threadIdx.x] - v;
        rowptr[i] = ex;
        cursor[i] = ex;
    }
}

// ---------------------------------------------------------------------------
// Merged GEMM + CSR-fill dispatch. Gemm body is the round-0-verified 128x128
// TK=32 kernel (82.8us L1, MfmaUtil 26.6%, 0 bank conflicts, 4 blocks/CU).
// Fill blocks (memory-latency-bound, VALU ~0.4%) are Bresenham-interleaved
// with gemm blocks so each CU co-hosts both: fill's scattered HBM traffic
// (16x write-amplified col[] scatter, ~56MB) runs in gemm's idle memory slots
// (gemm alone is 17% HBM). Exact bijection: block bid is fill iff
// floor((bid+1)*F/T) > floor(bid*F/T); fill idx = floor(bid*F/T), gemm idx =
// bid - fill idx. Deps: gemm needs prep (prior dispatch), fill needs cursor
// (scan_final2, prior dispatch); the common consumer k_agg_relu follows.
#define TM 128
#define TN 128
#define TK 32

template <int NCT, int SPLIT>
__global__ __launch_bounds__(256, 4)
void k_gemm_fill(const unsigned short* __restrict__ A, const unsigned short* __restrict__ W,
                 unsigned char* __restrict__ C8, unsigned short* __restrict__ C16,
                 int M, int K, int NC, int G, int F,
                 const int* __restrict__ s1, const int* __restrict__ d1,
                 const int* __restrict__ s2, const int* __restrict__ d2,
                 int* __restrict__ cur1, int* __restrict__ cur2,
                 int* __restrict__ col1, int* __restrict__ col2,
                 int E1, int E2, int EB) {
    __shared__ __align__(16) unsigned short As[TM * TK];
    __shared__ __align__(16) unsigned short Bs[TN * TK];

    const int bid = blockIdx.x;
    const long long T = (long long)G + F;
    const int pf = (int)(((long long)bid * F) / T);
    const bool isFill = (int)(((long long)(bid + 1) * F) / T) > pf;
    if (isFill) {
        const int f = pf;
        if (f < EB) {
            int e = f * 256 + threadIdx.x;
            if (e < E1) { int p = atomicAdd(&cur1[d1[e]], 1); col1[p] = s1[e]; }
        } else {
            int e = (f - EB) * 256 + threadIdx.x;
            if (e < E2) { int p = atomicAdd(&cur2[d2[e]], 1); col2[p] = s2[e]; }
        }
        return;
    }

    const int id = bid - pf;             // gemm block index, 0..G-1
    const int xcd = id & 7;
    const int s = id >> 3;
    const int row0 = ((s / NCT) * 8 + xcd) * TM;
    const int col0 = (s % NCT) * TN;
    if (row0 >= M) return;

    const int t = threadIdx.x;
    const int lane = t & 63;
    const int w = t >> 6;
    const int wr = (w >> 1) * 64;
    const int wc = (w & 1) * 64;
    const int lm = lane & 15;
    const int q = lane >> 4;             // logical k-chunk 0..3 (8 bf16 each)

    f32x4 acc[4][4];
#pragma unroll
    for (int i = 0; i < 4; ++i)
#pragma unroll
        for (int j = 0; j < 4; ++j) acc[i][j] = (f32x4){0.f, 0.f, 0.f, 0.f};

    // staging: LDS slot t holds row ar=t>>2, slot-chunk c=t&3; that slot must
    // receive global chunk sc = c ^ ((row>>1)&3) = (t&3) ^ ((t>>3)&3).
    const int ar = t >> 2;
    const int as = (((t & 3) ^ ((t >> 3) & 3))) * 8;

    for (int k0 = 0; k0 < K; k0 += TK) {
        int r1 = row0 + ar;      if (r1 >= M) r1 = M - 1;
        int r2 = row0 + ar + 64; if (r2 >= M) r2 = M - 1;
        const unsigned short* ga1 = A + (size_t)r1 * K + k0 + as;
        const unsigned short* ga2 = A + (size_t)r2 * K + k0 + as;
        const unsigned short* gb1 = W + (size_t)(col0 + ar) * K + k0 + as;
        const unsigned short* gb2 = W + (size_t)(col0 + ar + 64) * K + k0 + as;
        __builtin_amdgcn_global_load_lds(
            (const __attribute__((address_space(1))) unsigned int*)ga1,
            (__attribute__((address_space(3))) unsigned int*)&As[t * 8], 16, 0, 0);
        __builtin_amdgcn_global_load_lds(
            (const __attribute__((address_space(1))) unsigned int*)ga2,
            (__attribute__((address_space(3))) unsigned int*)&As[(t + 256) * 8], 16, 0, 0);
        __builtin_amdgcn_global_load_lds(
            (const __attribute__((address_space(1))) unsigned int*)gb1,
            (__attribute__((address_space(3))) unsigned int*)&Bs[t * 8], 16, 0, 0);
        __builtin_amdgcn_global_load_lds(
            (const __attribute__((address_space(1))) unsigned int*)gb2,
            (__attribute__((address_space(3))) unsigned int*)&Bs[(t + 256) * 8], 16, 0, 0);
        __syncthreads();

        short8 a[4], b[4];
#pragma unroll
        for (int i = 0; i < 4; ++i) {
            int R = wr + i * 16 + lm;
            a[i] = *(const short8*)&As[R * TK + ((q ^ ((R >> 1) & 3)) * 8)];
        }
#pragma unroll
        for (int j = 0; j < 4; ++j) {
            int R = wc + j * 16 + lm;
            b[j] = *(const short8*)&Bs[R * TK + ((q ^ ((R >> 1) & 3)) * 8)];
        }
#pragma unroll
        for (int i = 0; i < 4; ++i)
#pragma unroll
            for (int j = 0; j < 4; ++j)
                acc[i][j] = __builtin_amdgcn_mfma_f32_16x16x32_bf16(a[i], b[j], acc[i][j], 0, 0, 0);
        __syncthreads();
    }

    const int qr = (lane >> 4) * 4;
    const bool lo_half = SPLIT && (col0 < NC / 2);
    const int cadj = SPLIT ? NC / 2 : 0;
#pragma unroll
    for (int i = 0; i < 4; ++i) {
#pragma unroll
        for (int r = 0; r < 4; ++r) {
            int gr = row0 + wr + i * 16 + qr + r;
            if (gr >= M) continue;
#pragma unroll
            for (int j = 0; j < 4; ++j) {
                int gc = col0 + wc + j * 16 + lm;
                float v = acc[i][j][r];
                if (SPLIT && lo_half) {
                    int p = __builtin_amdgcn_cvt_pk_fp8_f32(v, v, 0, 0);
                    C8[(size_t)gr * (NC / 2) + gc] = (unsigned char)p;
                } else {
                    C16[(size_t)gr * (NC - cadj) + (gc - cadj)] = f2bf(v);
                }
            }
        }
    }
}

// Standalone gemm (layer 2) — identical body, no fill companion.
template <int NCT, int SPLIT>
__global__ __launch_bounds__(256, 4)
void k_gemm_mfma(const unsigned short* __restrict__ A, const unsigned short* __restrict__ W,
                 unsigned char* __restrict__ C8, unsigned short* __restrict__ C16,
                 int M, int K, int NC) {
    __shared__ __align__(16) unsigned short As[TM * TK];
    __shared__ __align__(16) unsigned short Bs[TN * TK];
    const int id = blockIdx.x;
    const int xcd = id & 7;
    const int s = id >> 3;
    const int row0 = ((s / NCT) * 8 + xcd) * TM;
    const int col0 = (s % NCT) * TN;
    if (row0 >= M) return;

    const int t = threadIdx.x;
    const int lane = t & 63;
    const int w = t >> 6;
    const int wr = (w >> 1) * 64;
    const int wc = (w & 1) * 64;
    const int lm = lane & 15;
    const int q = lane >> 4;

    f32x4 acc[4][4];
#pragma unroll
    for (int i = 0; i < 4; ++i)
#pragma unroll
        for (int j = 0; j < 4; ++j) acc[i][j] = (f32x4){0.f, 0.f, 0.f, 0.f};

    const int ar = t >> 2;
    const int as = (((t & 3) ^ ((t >> 3) & 3))) * 8;

    for (int k0 = 0; k0 < K; k0 += TK) {
        int r1 = row0 + ar;      if (r1 >= M) r1 = M - 1;
        int r2 = row0 + ar + 64; if (r2 >= M) r2 = M - 1;
        const unsigned short* ga1 = A + (size_t)r1 * K + k0 + as;
        const unsigned short* ga2 = A + (size_t)r2 * K + k0 + as;
        const unsigned short* gb1 = W + (size_t)(col0 + ar) * K + k0 + as;
        const unsigned short* gb2 = W + (size_t)(col0 + ar + 64) * K + k0 + as;
        __builtin_amdgcn_global_load_lds(
            (const __attribute__((address_space(1))) unsigned int*)ga1,
            (__attribute__((address_space(3))) unsigned int*)&As[t * 8], 16, 0, 0);
        __builtin_amdgcn_global_load_lds(
            (const __attribute__((address_space(1))) unsigned int*)ga2,
            (__attribute__((address_space(3))) unsigned int*)&As[(t + 256) * 8], 16, 0, 0);
        __builtin_amdgcn_global_load_lds(
            (const __attribute__((address_space(1))) unsigned int*)gb1,
            (__attribute__((address_space(3))) unsigned int*)&Bs[t * 8], 16, 0, 0);
        __builtin_amdgcn_global_load_lds(
            (const __attribute__((address_space(1))) unsigned int*)gb2,
            (__attribute__((address_space(3))) unsigned int*)&Bs[(t + 256) * 8], 16, 0, 0);
        __syncthreads();

        short8 a[4], b[4];
#pragma unroll
        for (int i = 0; i < 4; ++i) {
            int R = wr + i * 16 + lm;
            a[i] = *(const short8*)&As[R * TK + ((q ^ ((R >> 1) & 3)) * 8)];
        }
#pragma unroll
        for (int j = 0; j < 4; ++j) {
            int R = wc + j * 16 + lm;
            b[j] = *(const short8*)&Bs[R * TK + ((q ^ ((R >> 1) & 3)) * 8)];
        }
#pragma unroll
        for (int i = 0; i < 4; ++i)
#pragma unroll
            for (int j = 0; j < 4; ++j)
                acc[i][j] = __builtin_amdgcn_mfma_f32_16x16x32_bf16(a[i], b[j], acc[i][j], 0, 0, 0);
        __syncthreads();
    }

    const int qr = (lane >> 4) * 4;
    const bool lo_half = SPLIT && (col0 < NC / 2);
    const int cadj = SPLIT ? NC / 2 : 0;
#pragma unroll
    for (int i = 0; i < 4; ++i) {
#pragma unroll
        for (int r = 0; r < 4; ++r) {
            int gr = row0 + wr + i * 16 + qr + r;
            if (gr >= M) continue;
#pragma unroll
            for (int j = 0; j < 4; ++j) {
                int gc = col0 + wc + j * 16 + lm;
                float v = acc[i][j][r];
                if (SPLIT && lo_half) {
                    int p = __builtin_amdgcn_cvt_pk_fp8_f32(v, v, 0, 0);
                    C8[(size_t)gr * (NC / 2) + gc] = (unsigned char)p;
                } else {
                    C16[(size_t)gr * (NC - cadj) + (gc - cadj)] = f2bf(v);
                }
            }
        }
    }
}

// ---------------------------------------------------------------------------
// Layer-1 fused epilogue: h[i] = relu( mean_j C8[j] + C16r[i] + b1 ), bf16 out.
__global__ void k_agg_relu(const unsigned char* __restrict__ C8,
                           const unsigned short* __restrict__ C16r,
                           const int* __restrict__ rowptr, const int* __restrict__ col,
                           const float* __restrict__ b1, unsigned short* __restrict__ H, int n) {
    int node = blockIdx.x * (blockDim.x >> 6) + (threadIdx.x >> 6);
    int lane = threadIdx.x & 63;
    if (node >= n) return;
    int beg = rowptr[node], end = rowptr[node + 1];
    float acc[8] = {};
    const uint2* Cv = (const uint2*)C8;   // row stride 64 uint2
    int e = beg;
    for (; e + 4 <= end; e += 4) {
        int c0 = col[e], c1 = col[e + 1], c2 = col[e + 2], c3 = col[e + 3];
        uint2 v0 = Cv[(size_t)c0 * 64 + lane];
        uint2 v1 = Cv[(size_t)c1 * 64 + lane];
        uint2 v2 = Cv[(size_t)c2 * 64 + lane];
        uint2 v3 = Cv[(size_t)c3 * 64 + lane];
        unsigned int ws[8] = {v0.x, v0.y, v1.x, v1.y, v2.x, v2.y, v3.x, v3.y};
#pragma unroll
        for (int qq = 0; qq < 8; ++qq) {
            floatx2 flo = __builtin_amdgcn_cvt_pk_f32_fp8(ws[qq], 0);
            floatx2 fhi = __builtin_amdgcn_cvt_pk_f32_fp8(ws[qq], 1);
            int base = (qq & 1) * 4;
            acc[base + 0] += flo.x; acc[base + 1] += flo.y;
            acc[base + 2] += fhi.x; acc[base + 3] += fhi.y;
        }
    }
    for (; e < end; ++e) {
        uint2 v = Cv[(size_t)col[e] * 64 + lane];
        floatx2 f0 = __builtin_amdgcn_cvt_pk_f32_fp8(v.x, 0);
        floatx2 f1 = __builtin_amdgcn_cvt_pk_f32_fp8(v.x, 1);
        floatx2 f2 = __builtin_amdgcn_cvt_pk_f32_fp8(v.y, 0);
        floatx2 f3 = __builtin_amdgcn_cvt_pk_f32_fp8(v.y, 1);
        acc[0] += f0.x; acc[1] += f0.y; acc[2] += f1.x; acc[3] += f1.y;
        acc[4] += f2.x; acc[5] += f2.y; acc[6] += f3.x; acc[7] += f3.y;
    }
    float inv = 1.0f / fmaxf((float)(end - beg), 1.0f);
    uint4 yr = ((const uint4*)C16r)[(size_t)node * 64 + lane];
    unsigned int wr[4] = {yr.x, yr.y, yr.z, yr.w};
    float4 bv0 = ((const float4*)b1)[2 * lane];
    float4 bv1 = ((const float4*)b1)[2 * lane + 1];
    float bb[8] = {bv0.x, bv0.y, bv0.z, bv0.w, bv1.x, bv1.y, bv1.z, bv1.w};
    unsigned int r[4];
#pragma unroll
    for (int qq = 0; qq < 4; ++qq) {
        float v0 = fmaxf(acc[2 * qq] * inv     + bflo(wr[qq]) + bb[2 * qq],     0.f);
        float v1 = fmaxf(acc[2 * qq + 1] * inv + bfhi(wr[qq]) + bb[2 * qq + 1], 0.f);
        r[qq] = (unsigned)f2bf(v0) | ((unsigned)f2bf(v1) << 16);
    }
    uint4 o; o.x = r[0]; o.y = r[1]; o.z = r[2]; o.w = r[3];
    ((uint4*)H)[(size_t)node * 64 + lane] = o;
}

// ---------------------------------------------------------------------------
// Layer-2 fused epilogue: out[i] = log_softmax( mean_j C8[j] + C16r[i] + b2 ).
__global__ void k_agg_lsm(const unsigned char* __restrict__ C8,
                          const unsigned short* __restrict__ C16r,
                          const int* __restrict__ rowptr, const int* __restrict__ col,
                          const float* __restrict__ b2, float* __restrict__ O, int n) {
    int node = blockIdx.x * (blockDim.x >> 6) + (threadIdx.x >> 6);
    int lane = threadIdx.x & 63;
    if (node >= n) return;
    int beg = rowptr[node], end = rowptr[node + 1];
    float acc[4] = {};
    const unsigned int* Cv = (const unsigned int*)C8;   // row stride 64 uint
    int e = beg;
    for (; e + 4 <= end; e += 4) {
        int c0 = col[e], c1 = col[e + 1], c2 = col[e + 2], c3 = col[e + 3];
        unsigned int u0 = Cv[(size_t)c0 * 64 + lane];
        unsigned int u1 = Cv[(size_t)c1 * 64 + lane];
        unsigned int u2 = Cv[(size_t)c2 * 64 + lane];
        unsigned int u3 = Cv[(size_t)c3 * 64 + lane];
        unsigned int us[4] = {u0, u1, u2, u3};
#pragma unroll
        for (int qq = 0; qq < 4; ++qq) {
            floatx2 flo = __builtin_amdgcn_cvt_pk_f32_fp8(us[qq], 0);
            floatx2 fhi = __builtin_amdgcn_cvt_pk_f32_fp8(us[qq], 1);
            acc[0] += flo.x; acc[1] += flo.y; acc[2] += fhi.x; acc[3] += fhi.y;
        }
    }
    for (; e < end; ++e) {
        unsigned int u = Cv[(size_t)col[e] * 64 + lane];
        floatx2 flo = __builtin_amdgcn_cvt_pk_f32_fp8(u, 0);
        floatx2 fhi = __builtin_amdgcn_cvt_pk_f32_fp8(u, 1);
        acc[0] += flo.x; acc[1] += flo.y; acc[2] += fhi.x; acc[3] += fhi.y;
    }
    float inv = 1.0f / fmaxf((float)(end - beg), 1.0f);
    uint2 yr = ((const uint2*)C16r)[(size_t)node * 64 + lane];
    float4 bv = ((const float4*)b2)[lane];
    float val[4];
    val[0] = acc[0] * inv + bflo(yr.x) + bv.x;
    val[1] = acc[1] * inv + bfhi(yr.x) + bv.y;
    val[2] = acc[2] * inv + bflo(yr.y) + bv.z;
    val[3] = acc[3] * inv + bfhi(yr.y) + bv.w;
    float mx = fmaxf(fmaxf(val[0], val[1]), fmaxf(val[2], val[3]));
#pragma unroll
    for (int off = 32; off > 0; off >>= 1) mx = fmaxf(mx, __shfl_xor(mx, off));
    float s = expf(val[0] - mx) + expf(val[1] - mx) + expf(val[2] - mx) + expf(val[3] - mx);
#pragma unroll
    for (int off = 32; off > 0; off >>= 1) s += __shfl_xor(s, off);
    float lse = mx + logf(s);
    float4 o = make_float4(val[0] - lse, val[1] - lse, val[2] - lse, val[3] - lse);
    ((float4*)O)[(size_t)node * 64 + lane] = o;
}

// ---------------------------------------------------------------------------
extern "C" void kernel_launch(void* const* d_in, const int* in_sizes, int n_in,
                              void* d_out, int out_size, void* d_ws, size_t ws_size,
                              hipStream_t stream) {
    const float* x   = (const float*)d_in[0];
    const int*   ei1 = (const int*)d_in[1];
    const int*   ei2 = (const int*)d_in[2];
    const float* W1l = (const float*)d_in[3];
    const float* b1  = (const float*)d_in[4];
    const float* W1r = (const float*)d_in[5];
    const float* W2l = (const float*)d_in[6];
    const float* b2  = (const float*)d_in[7];
    const float* W2r = (const float*)d_in[8];
    float* out = (float*)d_out;

    const int N  = in_sizes[0] / DIN;
    const int E1 = in_sizes[1] / 2;
    const int E2 = in_sizes[2] / 2;
    const int Emax = (E1 > E2) ? E1 : E2;
    const int NB = (N + SCAN_B - 1) / SCAN_B;
    const int EB = (Emax + 255) / 256;

    // Workspace layout
    unsigned short* x_bf  = (unsigned short*)d_ws;             // N*512 bf16
    unsigned short* h_bf  = x_bf + (size_t)N * 512;            // N*512 bf16
    unsigned char*  c1l   = (unsigned char*)(h_bf + (size_t)N * 512);  // N*512 fp8
    unsigned short* c1r   = (unsigned short*)(c1l + (size_t)N * 512);  // N*512 bf16
    unsigned char*  c2l   = c1l;                               // N*256 fp8 (aliases c1)
    unsigned short* c2r   = (unsigned short*)(c2l + (size_t)N * 256);  // N*256 bf16
    unsigned short* w1_bf = c1r + (size_t)N * 512;             // 1024*512
    unsigned short* w2_bf = w1_bf + 1024 * 512;                // 512*512
    int* rowptr1 = (int*)(w2_bf + 512 * 512);                  // N+1
    int* rowptr2 = rowptr1 + (N + 1);                          // N+1
    int* cursor1 = rowptr2 + (N + 1);                          // N
    int* cursor2 = cursor1 + N;                                // N
    int* deg1    = cursor2 + N;                                // N
    int* deg2    = deg1 + N;                                   // N
    int* part1   = deg2 + N;                                   // 256
    int* part2   = part1 + 256;                                // 256
    int* col1    = part2 + 256;                                // E1
    int* col2    = col1 + E1;                                  // E2
    (void)ws_size; (void)n_in; (void)out_size;

    // deg zeroing, then fused conversions + degree count (count2 overlaps prep)
    hipMemsetAsync(deg1, 0, (size_t)2 * N * sizeof(int), stream);
    {
        int n8 = N * 512 / 8;
        int gb = (n8 + 98304 + 255) / 256 + 2 * EB;
        k_prep_cnt<<<gb, 256, 0, stream>>>(x, x_bf, W1l, W1r, W2l, W2r, w1_bf, w2_bf,
                                           ei1 + E1, ei2 + E2, deg1, deg2, n8, E1, E2, EB);
    }

    // scans (both layers batched)
    k_scan_partial2<<<dim3(NB, 2), SCAN_B, 0, stream>>>(deg1, deg2, part1, part2, N);
    k_scan_part2b<<<2, SCAN_B, 0, stream>>>(part1, part2, NB, rowptr1, rowptr2, N);
    k_scan_final2<<<dim3(NB, 2), SCAN_B, 0, stream>>>(deg1, deg2, part1, part2,
                                                      rowptr1, rowptr2, cursor1, cursor2, N);

    const int MB = (N + TM - 1) / TM;            // 391 row tiles
    const int G8 = (MB + 7) / 8;                 // 49 groups of 8

    // Layer 1 GEMM merged with BOTH layers' CSR fill (Bresenham-interleaved).
    {
        const int G = G8 * 8 * 8;                // 3136 gemm blocks (NCT=8)
        const int F = 2 * EB;                    // fill blocks, both layers
        k_gemm_fill<8, 1><<<G + F, 256, 0, stream>>>(
            x_bf, w1_bf, c1l, c1r, N, DIN, 1024, G, F,
            ei1, ei1 + E1, ei2, ei2 + E2, cursor1, cursor2, col1, col2, E1, E2, EB);
    }
    k_agg_relu<<<(N + 3) / 4, 256, 0, stream>>>(c1l, c1r, rowptr1, col1, b1, h_bf, N);

    // Layer 2: [y_l|y_r] = h @ [W2l;W2r]^T; y_l -> fp8, y_r -> bf16.
    k_gemm_mfma<4, 1><<<G8 * 8 * 4, 256, 0, stream>>>(h_bf, w2_bf, c2l, c2r, N, DHID, 512);
    k_agg_lsm<<<(N + 3) / 4, 256, 0, stream>>>(c2l, c2r, rowptr2, col2, b2, out, N);
}

// Round 9
// 439.806 us; speedup vs baseline: 1.2079x; 1.0320x over previous
//
#include <hip/hip_runtime.h>
#include <math.h>

#define DIN  512
#define DHID 512
#define DOUT 256

typedef __attribute__((ext_vector_type(8))) short short8;
typedef __attribute__((ext_vector_type(4))) float f32x4;
typedef __attribute__((ext_vector_type(2))) float floatx2;

__device__ __forceinline__ unsigned short f2bf(float f) {
    unsigned int u = __float_as_uint(f);
    u += 0x7fffu + ((u >> 16) & 1u);
    return (unsigned short)(u >> 16);
}
__device__ __forceinline__ float bflo(unsigned int w) { return __uint_as_float(w << 16); }
__device__ __forceinline__ float bfhi(unsigned int w) { return __uint_as_float(w & 0xffff0000u); }

// ---------------------------------------------------------------------------
// fp32 -> bf16, 8 elems per index i
__device__ __forceinline__ void cvt8(const float* __restrict__ in,
                                     unsigned short* __restrict__ out, int i) {
    const float4* iv = (const float4*)in;
    float4 a = iv[2 * i], b = iv[2 * i + 1];
    uint4 o;
    o.x = (unsigned)f2bf(a.x) | ((unsigned)f2bf(a.y) << 16);
    o.y = (unsigned)f2bf(a.z) | ((unsigned)f2bf(a.w) << 16);
    o.z = (unsigned)f2bf(b.x) | ((unsigned)f2bf(b.y) << 16);
    o.w = (unsigned)f2bf(b.z) | ((unsigned)f2bf(b.w) << 16);
    ((uint4*)out)[i] = o;
}

// Fused prep + degree count: x->bf16, four W->bf16, then appended blocks do
// the per-edge degree atomics for BOTH layers (deg zeroed by memset before).
__global__ void k_prep_cnt(const float* __restrict__ x, unsigned short* __restrict__ x_bf,
                           const float* __restrict__ W1l, const float* __restrict__ W1r,
                           const float* __restrict__ W2l, const float* __restrict__ W2r,
                           unsigned short* __restrict__ w1, unsigned short* __restrict__ w2,
                           const int* __restrict__ d1, const int* __restrict__ d2,
                           int* __restrict__ deg1, int* __restrict__ deg2,
                           int n8, int E1, int E2, int EB) {
    int i = blockIdx.x * blockDim.x + threadIdx.x;
    if (i < n8) { cvt8(x, x_bf, i); return; }
    i -= n8;
    if (i < 32768)  { cvt8(W1l, w1, i); return; }
    if (i < 65536)  { cvt8(W1r, w1 + 262144, i - 32768); return; }
    if (i < 81920)  { cvt8(W2l, w2, i - 65536); return; }
    if (i < 98304)  { cvt8(W2r, w2 + 131072, i - 81920); return; }
    i -= 98304;
    if (i < EB * 256) { if (i < E1) atomicAdd(&deg1[d1[i]], 1); return; }
    i -= EB * 256;
    if (i < E2) atomicAdd(&deg2[d2[i]], 1);
}

#define SCAN_B 256
__global__ void k_scan_partial2(const int* __restrict__ deg1, const int* __restrict__ deg2,
                                int* __restrict__ part1, int* __restrict__ part2, int n) {
    __shared__ int s[SCAN_B];
    const int* deg = blockIdx.y ? deg2 : deg1;
    int* part      = blockIdx.y ? part2 : part1;
    int i = blockIdx.x * SCAN_B + threadIdx.x;
    s[threadIdx.x] = (i < n) ? deg[i] : 0;
    __syncthreads();
    for (int off = SCAN_B / 2; off > 0; off >>= 1) {
        if (threadIdx.x < off) s[threadIdx.x] += s[threadIdx.x + off];
        __syncthreads();
    }
    if (threadIdx.x == 0) part[blockIdx.x] = s[0];
}

__global__ void k_scan_part2b(int* __restrict__ part1, int* __restrict__ part2, int nb,
                              int* __restrict__ rowptr1, int* __restrict__ rowptr2, int n) {
    __shared__ int s[SCAN_B];
    int* part   = blockIdx.x ? part2 : part1;
    int* rowptr = blockIdx.x ? rowptr2 : rowptr1;
    int v = (threadIdx.x < nb) ? part[threadIdx.x] : 0;
    s[threadIdx.x] = v;
    __syncthreads();
    for (int off = 1; off < SCAN_B; off <<= 1) {
        int t = (threadIdx.x >= off) ? s[threadIdx.x - off] : 0;
        __syncthreads();
        s[threadIdx.x] += t;
        __syncthreads();
    }
    if (threadIdx.x < nb) part[threadIdx.x] = s[threadIdx.x] - v;  // exclusive
    if (threadIdx.x == SCAN_B - 1) rowptr[n] = s[SCAN_B - 1];
}

__global__ void k_scan_final2(const int* __restrict__ deg1, const int* __restrict__ deg2,
                              const int* __restrict__ part1, const int* __restrict__ part2,
                              int* __restrict__ rowptr1, int* __restrict__ rowptr2,
                              int* __restrict__ cursor1, int* __restrict__ cursor2, int n) {
    __shared__ int s[SCAN_B];
    const int* deg  = blockIdx.y ? deg2 : deg1;
    const int* part = blockIdx.y ? part2 : part1;
    int* rowptr     = blockIdx.y ? rowptr2 : rowptr1;
    int* cursor     = blockIdx.y ? cursor2 : cursor1;
    int i = blockIdx.x * SCAN_B + threadIdx.x;
    int v = (i < n) ? deg[i] : 0;
    s[threadIdx.x] = v;
    __syncthreads();
    for (int off = 1; off < SCAN_B; off <<= 1) {
        int t = (threadIdx.x >= off) ? s[threadIdx.x - off] : 0;
        __syncthreads();
        s[threadIdx.x] += t;
        __syncthreads();
    }
    if (i < n) {
        int ex = part[blockIdx.x] + s[threadIdx.x] - v;
        rowptr[i] = ex;
        cursor[i] = ex;
    }
}

// ---------------------------------------------------------------------------
// GEMM tile body, TK=64 (vs round-0's TK=32): halves the per-block barrier/
// vmcnt-drain count (8 K-iters instead of 16) at the same total load count.
// LDS 32KB/block (As+Bs), still 4 blocks/CU at launch_bounds(256,4).
// Swizzle (8 chunks of 16B per 128B row): phys chunk = logical ^ (row&7).
// Fragment read: lanes sharing q have rows lm=0..15 -> groups q^(lm&7) = 2
// lanes/bank-group per quarter-wave (free, m136). Staging: thread t stages
// row L*32+(t>>3), slot t&7, from global chunk (t&7)^((t>>3)&7); dest is
// lane-linear (global_load_lds requirement). Fragments read in two k-step
// batches of 8 ds_read_b128 to keep live VGPRs ~120 (4 waves/SIMD budget).
#define TM 128
#define TN 128
#define TK 64

template <int NCT, int SPLIT>
__device__ __forceinline__ void gemm_tile(
        const unsigned short* __restrict__ A, const unsigned short* __restrict__ W,
        unsigned char* __restrict__ C8, unsigned short* __restrict__ C16,
        int M, int K, int NC, int id,
        unsigned short* __restrict__ As, unsigned short* __restrict__ Bs) {
    const int xcd = id & 7;
    const int s = id >> 3;
    const int row0 = ((s / NCT) * 8 + xcd) * TM;
    const int col0 = (s % NCT) * TN;
    if (row0 >= M) return;

    const int t = threadIdx.x;
    const int lane = t & 63;
    const int w = t >> 6;
    const int wr = (w >> 1) * 64;
    const int wc = (w & 1) * 64;
    const int lm = lane & 15;
    const int q = lane >> 4;             // logical k-chunk 0..3 (8 bf16 each)

    f32x4 acc[4][4];
#pragma unroll
    for (int i = 0; i < 4; ++i)
#pragma unroll
        for (int j = 0; j < 4; ++j) acc[i][j] = (f32x4){0.f, 0.f, 0.f, 0.f};

    // staging geometry
    const int sr = t >> 3;                    // 0..31 (row within 32-row segment)
    const int sc = t & 7;                     // chunk slot 0..7
    const int gx = (sc ^ (sr & 7)) * 8;       // inverse-swizzled source chunk

    #define GL(SRC, DST) __builtin_amdgcn_global_load_lds( \
        (const __attribute__((address_space(1))) unsigned int*)(SRC), \
        (__attribute__((address_space(3))) unsigned int*)(DST), 16, 0, 0)

    for (int k0 = 0; k0 < K; k0 += TK) {
#pragma unroll
        for (int L = 0; L < 4; ++L) {
            int ra = row0 + L * 32 + sr; if (ra >= M) ra = M - 1;
            GL(A + (size_t)ra * K + k0 + gx, &As[L * 2048 + t * 8]);
        }
#pragma unroll
        for (int L = 0; L < 4; ++L) {
            int rb = col0 + L * 32 + sr;      // W rows always in range
            GL(W + (size_t)rb * K + k0 + gx, &Bs[L * 2048 + t * 8]);
        }
        __syncthreads();

        short8 a[4], b[4];
        // k-step 0: logical chunks q
#pragma unroll
        for (int i = 0; i < 4; ++i) {
            int R = wr + i * 16 + lm;
            a[i] = *(const short8*)&As[R * TK + ((q ^ (R & 7)) * 8)];
        }
#pragma unroll
        for (int j = 0; j < 4; ++j) {
            int R = wc + j * 16 + lm;
            b[j] = *(const short8*)&Bs[R * TK + ((q ^ (R & 7)) * 8)];
        }
#pragma unroll
        for (int i = 0; i < 4; ++i)
#pragma unroll
            for (int j = 0; j < 4; ++j)
                acc[i][j] = __builtin_amdgcn_mfma_f32_16x16x32_bf16(a[i], b[j], acc[i][j], 0, 0, 0);
        // k-step 1: logical chunks 4+q (reuse registers)
#pragma unroll
        for (int i = 0; i < 4; ++i) {
            int R = wr + i * 16 + lm;
            a[i] = *(const short8*)&As[R * TK + (((4 + q) ^ (R & 7)) * 8)];
        }
#pragma unroll
        for (int j = 0; j < 4; ++j) {
            int R = wc + j * 16 + lm;
            b[j] = *(const short8*)&Bs[R * TK + (((4 + q) ^ (R & 7)) * 8)];
        }
#pragma unroll
        for (int i = 0; i < 4; ++i)
#pragma unroll
            for (int j = 0; j < 4; ++j)
                acc[i][j] = __builtin_amdgcn_mfma_f32_16x16x32_bf16(a[i], b[j], acc[i][j], 0, 0, 0);
        __syncthreads();
    }
    #undef GL

    // epilogue: D row = quad*4 + reg, col = lane&15. col0 is 128-aligned so
    // the fp8/bf16 split (at NC/2) is block-uniform.
    const int qr = (lane >> 4) * 4;
    const bool lo_half = SPLIT && (col0 < NC / 2);
    const int cadj = SPLIT ? NC / 2 : 0;
#pragma unroll
    for (int i = 0; i < 4; ++i) {
#pragma unroll
        for (int r = 0; r < 4; ++r) {
            int gr = row0 + wr + i * 16 + qr + r;
            if (gr >= M) continue;
#pragma unroll
            for (int j = 0; j < 4; ++j) {
                int gc = col0 + wc + j * 16 + lm;
                float v = acc[i][j][r];
                if (SPLIT && lo_half) {
                    int p = __builtin_amdgcn_cvt_pk_fp8_f32(v, v, 0, 0);
                    C8[(size_t)gr * (NC / 2) + gc] = (unsigned char)p;
                } else {
                    C16[(size_t)gr * (NC - cadj) + (gc - cadj)] = f2bf(v);
                }
            }
        }
    }
}

// Merged GEMM + CSR-fill (Bresenham-interleaved; see round-7 notes). The
// col[] scatter now uses NON-TEMPORAL stores: no-allocate keeps the 4B
// scatters from evicting the gemm's A/W working set out of L2/L3 (round-7
// counters: FETCH 135MB vs 40MB sum-of-parts = cache-interference tax).
template <int NCT, int SPLIT>
__global__ __launch_bounds__(256, 4)
void k_gemm_fill(const unsigned short* __restrict__ A, const unsigned short* __restrict__ W,
                 unsigned char* __restrict__ C8, unsigned short* __restrict__ C16,
                 int M, int K, int NC, int G, int F,
                 const int* __restrict__ s1, const int* __restrict__ d1,
                 const int* __restrict__ s2, const int* __restrict__ d2,
                 int* __restrict__ cur1, int* __restrict__ cur2,
                 int* __restrict__ col1, int* __restrict__ col2,
                 int E1, int E2, int EB) {
    __shared__ __align__(16) unsigned short As[TM * TK];
    __shared__ __align__(16) unsigned short Bs[TN * TK];

    const int bid = blockIdx.x;
    const long long T = (long long)G + F;
    const int pf = (int)(((long long)bid * F) / T);
    const bool isFill = (int)(((long long)(bid + 1) * F) / T) > pf;
    if (isFill) {
        const int f = pf;
        if (f < EB) {
            int e = f * 256 + threadIdx.x;
            if (e < E1) {
                int p = atomicAdd(&cur1[d1[e]], 1);
                __builtin_nontemporal_store(s1[e], &col1[p]);
            }
        } else {
            int e = (f - EB) * 256 + threadIdx.x;
            if (e < E2) {
                int p = atomicAdd(&cur2[d2[e]], 1);
                __builtin_nontemporal_store(s2[e], &col2[p]);
            }
        }
        return;
    }
    gemm_tile<NCT, SPLIT>(A, W, C8, C16, M, K, NC, bid - pf, As, Bs);
}

// Standalone gemm (layer 2) — identical body.
template <int NCT, int SPLIT>
__global__ __launch_bounds__(256, 4)
void k_gemm_mfma(const unsigned short* __restrict__ A, const unsigned short* __restrict__ W,
                 unsigned char* __restrict__ C8, unsigned short* __restrict__ C16,
                 int M, int K, int NC) {
    __shared__ __align__(16) unsigned short As[TM * TK];
    __shared__ __align__(16) unsigned short Bs[TN * TK];
    gemm_tile<NCT, SPLIT>(A, W, C8, C16, M, K, NC, blockIdx.x, As, Bs);
}

// ---------------------------------------------------------------------------
// Layer-1 fused epilogue: h[i] = relu( mean_j C8[j] + C16r[i] + b1 ), bf16 out.
__global__ void k_agg_relu(const unsigned char* __restrict__ C8,
                           const unsigned short* __restrict__ C16r,
                           const int* __restrict__ rowptr, const int* __restrict__ col,
                           const float* __restrict__ b1, unsigned short* __restrict__ H, int n) {
    int node = blockIdx.x * (blockDim.x >> 6) + (threadIdx.x >> 6);
    int lane = threadIdx.x & 63;
    if (node >= n) return;
    int beg = rowptr[node], end = rowptr[node + 1];
    float acc[8] = {};
    const uint2* Cv = (const uint2*)C8;   // row stride 64 uint2
    int e = beg;
    for (; e + 4 <= end; e += 4) {
        int c0 = col[e], c1 = col[e + 1], c2 = col[e + 2], c3 = col[e + 3];
        uint2 v0 = Cv[(size_t)c0 * 64 + lane];
        uint2 v1 = Cv[(size_t)c1 * 64 + lane];
        uint2 v2 = Cv[(size_t)c2 * 64 + lane];
        uint2 v3 = Cv[(size_t)c3 * 64 + lane];
        unsigned int ws[8] = {v0.x, v0.y, v1.x, v1.y, v2.x, v2.y, v3.x, v3.y};
#pragma unroll
        for (int qq = 0; qq < 8; ++qq) {
            floatx2 flo = __builtin_amdgcn_cvt_pk_f32_fp8(ws[qq], 0);
            floatx2 fhi = __builtin_amdgcn_cvt_pk_f32_fp8(ws[qq], 1);
            int base = (qq & 1) * 4;
            acc[base + 0] += flo.x; acc[base + 1] += flo.y;
            acc[base + 2] += fhi.x; acc[base + 3] += fhi.y;
        }
    }
    for (; e < end; ++e) {
        uint2 v = Cv[(size_t)col[e] * 64 + lane];
        floatx2 f0 = __builtin_amdgcn_cvt_pk_f32_fp8(v.x, 0);
        floatx2 f1 = __builtin_amdgcn_cvt_pk_f32_fp8(v.x, 1);
        floatx2 f2 = __builtin_amdgcn_cvt_pk_f32_fp8(v.y, 0);
        floatx2 f3 = __builtin_amdgcn_cvt_pk_f32_fp8(v.y, 1);
        acc[0] += f0.x; acc[1] += f0.y; acc[2] += f1.x; acc[3] += f1.y;
        acc[4] += f2.x; acc[5] += f2.y; acc[6] += f3.x; acc[7] += f3.y;
    }
    float inv = 1.0f / fmaxf((float)(end - beg), 1.0f);
    uint4 yr = ((const uint4*)C16r)[(size_t)node * 64 + lane];
    unsigned int wr[4] = {yr.x, yr.y, yr.z, yr.w};
    float4 bv0 = ((const float4*)b1)[2 * lane];
    float4 bv1 = ((const float4*)b1)[2 * lane + 1];
    float bb[8] = {bv0.x, bv0.y, bv0.z, bv0.w, bv1.x, bv1.y, bv1.z, bv1.w};
    unsigned int r[4];
#pragma unroll
    for (int qq = 0; qq < 4; ++qq) {
        float v0 = fmaxf(acc[2 * qq] * inv     + bflo(wr[qq]) + bb[2 * qq],     0.f);
        float v1 = fmaxf(acc[2 * qq + 1] * inv + bfhi(wr[qq]) + bb[2 * qq + 1], 0.f);
        r[qq] = (unsigned)f2bf(v0) | ((unsigned)f2bf(v1) << 16);
    }
    uint4 o; o.x = r[0]; o.y = r[1]; o.z = r[2]; o.w = r[3];
    ((uint4*)H)[(size_t)node * 64 + lane] = o;
}

// ---------------------------------------------------------------------------
// Layer-2 fused epilogue: out[i] = log_softmax( mean_j C8[j] + C16r[i] + b2 ).
__global__ void k_agg_lsm(const unsigned char* __restrict__ C8,
                          const unsigned short* __restrict__ C16r,
                          const int* __restrict__ rowptr, const int* __restrict__ col,
                          const float* __restrict__ b2, float* __restrict__ O, int n) {
    int node = blockIdx.x * (blockDim.x >> 6) + (threadIdx.x >> 6);
    int lane = threadIdx.x & 63;
    if (node >= n) return;
    int beg = rowptr[node], end = rowptr[node + 1];
    float acc[4] = {};
    const unsigned int* Cv = (const unsigned int*)C8;   // row stride 64 uint
    int e = beg;
    for (; e + 4 <= end; e += 4) {
        int c0 = col[e], c1 = col[e + 1], c2 = col[e + 2], c3 = col[e + 3];
        unsigned int u0 = Cv[(size_t)c0 * 64 + lane];
        unsigned int u1 = Cv[(size_t)c1 * 64 + lane];
        unsigned int u2 = Cv[(size_t)c2 * 64 + lane];
        unsigned int u3 = Cv[(size_t)c3 * 64 + lane];
        unsigned int us[4] = {u0, u1, u2, u3};
#pragma unroll
        for (int qq = 0; qq < 4; ++qq) {
            floatx2 flo = __builtin_amdgcn_cvt_pk_f32_fp8(us[qq], 0);
            floatx2 fhi = __builtin_amdgcn_cvt_pk_f32_fp8(us[qq], 1);
            acc[0] += flo.x; acc[1] += flo.y; acc[2] += fhi.x; acc[3] += fhi.y;
        }
    }
    for (; e < end; ++e) {
        unsigned int u = Cv[(size_t)col[e] * 64 + lane];
        floatx2 flo = __builtin_amdgcn_cvt_pk_f32_fp8(u, 0);
        floatx2 fhi = __builtin_amdgcn_cvt_pk_f32_fp8(u, 1);
        acc[0] += flo.x; acc[1] += flo.y; acc[2] += fhi.x; acc[3] += fhi.y;
    }
    float inv = 1.0f / fmaxf((float)(end - beg), 1.0f);
    uint2 yr = ((const uint2*)C16r)[(size_t)node * 64 + lane];
    float4 bv = ((const float4*)b2)[lane];
    float val[4];
    val[0] = acc[0] * inv + bflo(yr.x) + bv.x;
    val[1] = acc[1] * inv + bfhi(yr.x) + bv.y;
    val[2] = acc[2] * inv + bflo(yr.y) + bv.z;
    val[3] = acc[3] * inv + bfhi(yr.y) + bv.w;
    float mx = fmaxf(fmaxf(val[0], val[1]), fmaxf(val[2], val[3]));
#pragma unroll
    for (int off = 32; off > 0; off >>= 1) mx = fmaxf(mx, __shfl_xor(mx, off));
    float s = expf(val[0] - mx) + expf(val[1] - mx) + expf(val[2] - mx) + expf(val[3] - mx);
#pragma unroll
    for (int off = 32; off > 0; off >>= 1) s += __shfl_xor(s, off);
    float lse = mx + logf(s);
    float4 o = make_float4(val[0] - lse, val[1] - lse, val[2] - lse, val[3] - lse);
    ((float4*)O)[(size_t)node * 64 + lane] = o;
}

// ---------------------------------------------------------------------------
extern "C" void kernel_launch(void* const* d_in, const int* in_sizes, int n_in,
                              void* d_out, int out_size, void* d_ws, size_t ws_size,
                              hipStream_t stream) {
    const float* x   = (const float*)d_in[0];
    const int*   ei1 = (const int*)d_in[1];
    const int*   ei2 = (const int*)d_in[2];
    const float* W1l = (const float*)d_in[3];
    const float* b1  = (const float*)d_in[4];
    const float* W1r = (const float*)d_in[5];
    const float* W2l = (const float*)d_in[6];
    const float* b2  = (const float*)d_in[7];
    const float* W2r = (const float*)d_in[8];
    float* out = (float*)d_out;

    const int N  = in_sizes[0] / DIN;
    const int E1 = in_sizes[1] / 2;
    const int E2 = in_sizes[2] / 2;
    const int Emax = (E1 > E2) ? E1 : E2;
    const int NB = (N + SCAN_B - 1) / SCAN_B;
    const int EB = (Emax + 255) / 256;

    // Workspace layout
    unsigned short* x_bf  = (unsigned short*)d_ws;             // N*512 bf16
    unsigned short* h_bf  = x_bf + (size_t)N * 512;            // N*512 bf16
    unsigned char*  c1l   = (unsigned char*)(h_bf + (size_t)N * 512);  // N*512 fp8
    unsigned short* c1r   = (unsigned short*)(c1l + (size_t)N * 512);  // N*512 bf16
    unsigned char*  c2l   = c1l;                               // N*256 fp8 (aliases c1)
    unsigned short* c2r   = (unsigned short*)(c2l + (size_t)N * 256);  // N*256 bf16
    unsigned short* w1_bf = c1r + (size_t)N * 512;             // 1024*512
    unsigned short* w2_bf = w1_bf + 1024 * 512;                // 512*512
    int* rowptr1 = (int*)(w2_bf + 512 * 512);                  // N+1
    int* rowptr2 = rowptr1 + (N + 1);                          // N+1
    int* cursor1 = rowptr2 + (N + 1);                          // N
    int* cursor2 = cursor1 + N;                                // N
    int* deg1    = cursor2 + N;                                // N
    int* deg2    = deg1 + N;                                   // N
    int* part1   = deg2 + N;                                   // 256
    int* part2   = part1 + 256;                                // 256
    int* col1    = part2 + 256;                                // E1
    int* col2    = col1 + E1;                                  // E2
    (void)ws_size; (void)n_in; (void)out_size;

    // deg zeroing, then fused conversions + degree count (count2 overlaps prep)
    hipMemsetAsync(deg1, 0, (size_t)2 * N * sizeof(int), stream);
    {
        int n8 = N * 512 / 8;
        int gb = (n8 + 98304 + 255) / 256 + 2 * EB;
        k_prep_cnt<<<gb, 256, 0, stream>>>(x, x_bf, W1l, W1r, W2l, W2r, w1_bf, w2_bf,
                                           ei1 + E1, ei2 + E2, deg1, deg2, n8, E1, E2, EB);
    }

    // scans (both layers batched)
    k_scan_partial2<<<dim3(NB, 2), SCAN_B, 0, stream>>>(deg1, deg2, part1, part2, N);
    k_scan_part2b<<<2, SCAN_B, 0, stream>>>(part1, part2, NB, rowptr1, rowptr2, N);
    k_scan_final2<<<dim3(NB, 2), SCAN_B, 0, stream>>>(deg1, deg2, part1, part2,
                                                      rowptr1, rowptr2, cursor1, cursor2, N);

    const int MB = (N + TM - 1) / TM;            // 391 row tiles
    const int G8 = (MB + 7) / 8;                 // 49 groups of 8

    // Layer 1 GEMM merged with BOTH layers' CSR fill (Bresenham-interleaved).
    {
        const int G = G8 * 8 * 8;                // 3136 gemm blocks (NCT=8)
        const int F = 2 * EB;                    // fill blocks, both layers
        k_gemm_fill<8, 1><<<G + F, 256, 0, stream>>>(
            x_bf, w1_bf, c1l, c1r, N, DIN, 1024, G, F,
            ei1, ei1 + E1, ei2, ei2 + E2, cursor1, cursor2, col1, col2, E1, E2, EB);
    }
    k_agg_relu<<<(N + 3) / 4, 256, 0, stream>>>(c1l, c1r, rowptr1, col1, b1, h_bf, N);

    // Layer 2: [y_l|y_r] = h @ [W2l;W2r]^T; y_l -> fp8, y_r -> bf16.
    k_gemm_mfma<4, 1><<<G8 * 8 * 4, 256, 0, stream>>>(h_bf, w2_bf, c2l, c2r, N, DHID, 512);
    k_agg_lsm<<<(N + 3) / 4, 256, 0, stream>>>(c2l, c2r, rowptr2, col2, b2, out, N);
}